// Round 15
// baseline (1601.582 us; speedup 1.0000x reference)
//
#include <hip/hip_runtime.h>

#define N_NODES 32768
#define DEG 16
#define IN_F 128
#define HIDF 256
#define N_GRAPHS 256
#define NPG 128
#define OUT_F 16

typedef unsigned short u16;
typedef unsigned int u32;
typedef __bf16 bf16x8 __attribute__((ext_vector_type(8)));
typedef float f32x4 __attribute__((ext_vector_type(4)));
typedef u16 u16x4 __attribute__((ext_vector_type(4)));
typedef u16 u16x8 __attribute__((ext_vector_type(8)));

__device__ __forceinline__ u16 f2bf(float f) {
  union { float f; unsigned u; } v; v.f = f;
  return (u16)((v.u + 0x7FFFu + ((v.u >> 16) & 1u)) >> 16);
}
__device__ __forceinline__ float bf2f(u16 b) {
  union { unsigned u; float f; } v; v.u = ((unsigned)b) << 16;
  return v.f;
}
__device__ __forceinline__ float sigm(float x) { return 1.0f / (1.0f + __expf(-x)); }
__device__ __forceinline__ float tanhfast(float x) {
  float e = __expf(2.0f * x);
  return (e - 1.0f) / (e + 1.0f);
}

// ---- prep kernels -------------------------------------------------------

__global__ void k_prep_x(const float* __restrict__ x, u16* __restrict__ out, int n4) {
  int i = blockIdx.x * blockDim.x + threadIdx.x;
  if (i < n4) {
    float4 v = ((const float4*)x)[i];
    ushort4 o;
    o.x = f2bf(v.x); o.y = f2bf(v.y); o.z = f2bf(v.z); o.w = f2bf(v.w);
    ((ushort4*)out)[i] = o;
  }
}

// Whp: gate-interleaved rows p = fe*4 + gate (MFMA C-fragment j == gate).
// Wip/bwp: additionally lq-major WITHIN each 64-row slice, so a gather
// thread's 16 values (4 fe x 4 gates) are 32B contiguous:
//   new local q = lq*16 + mt*4 + gate  <->  old local = mt*16 + lq*4 + gate
__global__ void k_prep_wg(const float* __restrict__ Wi, const float* __restrict__ Wh,
                          const float* __restrict__ bi, const float* __restrict__ bh,
                          u16* __restrict__ Wip, u16* __restrict__ Whp,
                          float* __restrict__ bwp, int F) {
  int total = 4 * F * F;
  for (int idx = blockIdx.x * blockDim.x + threadIdx.x; idx < total;
       idx += gridDim.x * blockDim.x) {
    int p = idx / F, k = idx % F;
    {  // Whp: plain gate-interleaved rows
      int fe = p >> 2, g = p & 3;
      int orig = g * F + fe;
      Whp[idx] = f2bf(Wh[orig * F + k]);
    }
    {  // Wip + bwp: lq-major slice order
      int base = p & ~63, local = p & 63;
      int lq = local >> 4, mt = (local >> 2) & 3, gate = local & 3;
      int oldp = base + mt * 16 + lq * 4 + gate;
      int fe = oldp >> 2, g = oldp & 3;
      int orig = g * F + fe;
      Wip[idx] = f2bf(Wi[orig * F + k]);
      if (k == 0) bwp[p] = bi[orig] + bh[orig];
    }
  }
}

__global__ void k_prep_cast(const float* __restrict__ Ws, const float* __restrict__ Wn,
                            u16* __restrict__ Bs, u16* __restrict__ Bn, int n) {
  int i = blockIdx.x * blockDim.x + threadIdx.x;
  if (i < n) { Bs[i] = f2bf(Ws[i]); Bn[i] = f2bf(Wn[i]); }
}

// ---- dense GEMM: C[M][NC] = bf16(A[M][K] @ B[NC][K]^T + bias) ------------
template <int K, int NC>
__launch_bounds__(256, 4)
__global__ void k_gemm(const u16* __restrict__ A, const u16* __restrict__ B,
                       const float* __restrict__ bias, u16* __restrict__ C) {
  constexpr int ROWB = 2 * K;
  __shared__ u16 lds[64 * K];
  char* ldsb = (char*)lds;
  const int tid = threadIdx.x;
  const int w = tid >> 6;
  const int lane = tid & 63;
  const int l16 = lane & 15, lq = lane >> 4;
  const int row0 = blockIdx.x * 64;
  const int col0 = blockIdx.y * 128;

  constexpr int CH = K / 8;
  constexpr int RPI = 256 / CH;
#pragma unroll
  for (int it = 0; it < 64 / RPI; ++it) {
    int r = tid / CH + it * RPI;
    int ch = tid % CH;
    bf16x8 v = *(const bf16x8*)(A + (size_t)(row0 + r) * K + ch * 8);
    int bo = r * ROWB + ((ch * 16) ^ ((r & 7) << 4));
    *(bf16x8*)(ldsb + bo) = v;
  }
  __syncthreads();

  f32x4 acc[4][2];
#pragma unroll
  for (int mt = 0; mt < 4; ++mt)
#pragma unroll
    for (int nt = 0; nt < 2; ++nt)
#pragma unroll
      for (int j = 0; j < 4; ++j) acc[mt][nt][j] = 0.f;

  for (int ks = 0; ks < K / 32; ++ks) {
    bf16x8 a[4];
#pragma unroll
    for (int mt = 0; mt < 4; ++mt) {
      int r = mt * 16 + l16;
      int bo = r * ROWB + (((ks * 32 + lq * 8) * 2) ^ ((r & 7) << 4));
      a[mt] = *(const bf16x8*)(ldsb + bo);
    }
#pragma unroll
    for (int nt = 0; nt < 2; ++nt) {
      int coln = col0 + w * 32 + nt * 16 + l16;
      bf16x8 b = *(const bf16x8*)(B + (size_t)coln * K + ks * 32 + lq * 8);
#pragma unroll
      for (int mt = 0; mt < 4; ++mt)
        acc[mt][nt] = __builtin_amdgcn_mfma_f32_16x16x32_bf16(a[mt], b, acc[mt][nt], 0, 0, 0);
    }
  }
#pragma unroll
  for (int mt = 0; mt < 4; ++mt)
#pragma unroll
    for (int nt = 0; nt < 2; ++nt) {
      int coln = col0 + w * 32 + nt * 16 + l16;
      float bb = bias[coln];
#pragma unroll
      for (int j = 0; j < 4; ++j) {
        int r = row0 + mt * 16 + lq * 4 + j;
        C[(size_t)r * NC + coln] = f2bf(acc[mt][nt][j] + bb);
      }
    }
}

// ---- combine GEMM: C[r][coln] = relu_bf16(XS[r][coln] + A[r]@B[coln]) ----
template <int K>
__launch_bounds__(256, 4)
__global__ void k_comb(const u16* __restrict__ A, const u16* __restrict__ B,
                       const u16* __restrict__ XS, u16* __restrict__ C) {
  constexpr int ROWB = 2 * K;
  __shared__ u16 lds[64 * K];
  char* ldsb = (char*)lds;
  const int tid = threadIdx.x;
  const int w = tid >> 6;
  const int lane = tid & 63;
  const int l16 = lane & 15, lq = lane >> 4;
  const int row0 = blockIdx.x * 64;
  const int col0 = blockIdx.y * 128;

  constexpr int CH = K / 8;
  constexpr int RPI = 256 / CH;
#pragma unroll
  for (int it = 0; it < 64 / RPI; ++it) {
    int r = tid / CH + it * RPI;
    int ch = tid % CH;
    bf16x8 v = *(const bf16x8*)(A + (size_t)(row0 + r) * K + ch * 8);
    int bo = r * ROWB + ((ch * 16) ^ ((r & 7) << 4));
    *(bf16x8*)(ldsb + bo) = v;
  }
  __syncthreads();

  f32x4 acc[4][2];
#pragma unroll
  for (int mt = 0; mt < 4; ++mt)
#pragma unroll
    for (int nt = 0; nt < 2; ++nt)
#pragma unroll
      for (int j = 0; j < 4; ++j) acc[mt][nt][j] = 0.f;

  for (int ks = 0; ks < K / 32; ++ks) {
    bf16x8 a[4];
#pragma unroll
    for (int mt = 0; mt < 4; ++mt) {
      int r = mt * 16 + l16;
      int bo = r * ROWB + (((ks * 32 + lq * 8) * 2) ^ ((r & 7) << 4));
      a[mt] = *(const bf16x8*)(ldsb + bo);
    }
#pragma unroll
    for (int nt = 0; nt < 2; ++nt) {
      int coln = col0 + w * 32 + nt * 16 + l16;
      bf16x8 b = *(const bf16x8*)(B + (size_t)coln * K + ks * 32 + lq * 8);
#pragma unroll
      for (int mt = 0; mt < 4; ++mt)
        acc[mt][nt] = __builtin_amdgcn_mfma_f32_16x16x32_bf16(a[mt], b, acc[mt][nt], 0, 0, 0);
    }
  }
#pragma unroll
  for (int mt = 0; mt < 4; ++mt)
#pragma unroll
    for (int nt = 0; nt < 2; ++nt) {
      int coln = col0 + w * 32 + nt * 16 + l16;
#pragma unroll
      for (int j = 0; j < 4; ++j) {
        int r = row0 + mt * 16 + lq * 4 + j;
        float v = acc[mt][nt][j] + bf2f(XS[(size_t)r * HIDF + coln]);
        C[(size_t)r * HIDF + coln] = f2bf(fmaxf(v, 0.f));
      }
    }
}

// ---- whole-layer LSTM aggregation: all DEG steps in one launch ----------
// KEY INSIGHT: the recurrence is PER-NODE (x is gathered from the FIXED
// layer input; h,c are node-local), so a block owning ALL 4F gate rows for
// its NT=128 nodes runs all 16 steps internally:
//  - h double-buffered in swizzled LDS (never touches global),
//  - c in REGISTERS across all steps,
//  - per-step traffic = the XW random gather only,
//  - W streams from the L2-resident Whp (512KB),
//  - ONE barrier per step.
// Per step, each of 8 waves runs ST=F/64 subtiles of the round-13-verified
// 64-row x 64-node shape (acc[4][4], lq-major xw gather, j==gate cell).
// All gathers issue at step start -> full-step latency window.
template <int F>
__launch_bounds__(512, 1)
__global__ void k_layer(const u16* __restrict__ XW,   // [N][4F] lq-major slices, bias folded
                        const u16* __restrict__ Whp,  // [4F][F] gate-interleaved rows
                        const int* __restrict__ nbr,  // [N][DEG]
                        u16* __restrict__ hout) {     // [N][F]
  constexpr int NT = 128;
  constexpr int ROWB = 2 * F;
  constexpr int KS = F / 32;
  constexpr int ST = F / 64;   // subtiles per wave (4 for F=256, 2 for F=128)
  __shared__ __align__(16) u16 hbuf[2][NT * F];
  __shared__ int snbrT[DEG * NT];
  const int tid = threadIdx.x;
  const int w = tid >> 6;
  const int lane = tid & 63;
  const int l16 = lane & 15, lq = lane >> 4;
  const int nodeg = blockIdx.x * NT;

  // stage transposed neighbor table (coalesced once)
  for (int idx = tid; idx < DEG * NT; idx += 512) {
    int nl = idx / DEG, tt = idx % DEG;
    snbrT[tt * NT + nl] = nbr[(size_t)(nodeg + nl) * DEG + tt];
  }

  float c[ST][4][4];
#pragma unroll
  for (int i = 0; i < ST; ++i)
#pragma unroll
    for (int mt = 0; mt < 4; ++mt)
#pragma unroll
      for (int nt = 0; nt < 4; ++nt) c[i][mt][nt] = 0.f;

  __syncthreads();

#pragma unroll 1
  for (int t = 0; t < DEG; ++t) {
    const char* hrd = (const char*)hbuf[t & 1];
    char* hwr = (char*)hbuf[(t & 1) ^ 1];

    // issue ALL subtile gathers for this step up front
    u16x8 xwall[ST][4][2];
#pragma unroll
    for (int i = 0; i < ST; ++i) {
      int s = w * ST + i;
      int rs = s >> 1, ns2 = s & 1;
#pragma unroll
      for (int nt = 0; nt < 4; ++nt) {
        int nl = ns2 * 64 + nt * 16 + l16;
        int nb = snbrT[t * NT + nl];
        const u16* bptr = XW + (size_t)nb * (4 * F) + rs * 64 + lq * 16;
        xwall[i][nt][0] = *(const u16x8*)(bptr);
        xwall[i][nt][1] = *(const u16x8*)(bptr + 8);
      }
    }

#pragma unroll
    for (int i = 0; i < ST; ++i) {
      int s = w * ST + i;
      int rs = s >> 1, ns2 = s & 1;
      int nbl = ns2 * 64;

      f32x4 acc[4][4];
#pragma unroll
      for (int mt = 0; mt < 4; ++mt)
#pragma unroll
        for (int nt = 0; nt < 4; ++nt)
#pragma unroll
          for (int j = 0; j < 4; ++j) acc[mt][nt][j] = 0.f;

      if (t > 0) {
        const u16* wb = Whp + (size_t)(rs * 64 + l16) * F + lq * 8;
#pragma unroll
        for (int ks = 0; ks < KS; ++ks) {
          bf16x8 a[4];
#pragma unroll
          for (int mt = 0; mt < 4; ++mt)
            a[mt] = *(const bf16x8*)(wb + (size_t)mt * 16 * F + ks * 32);
          bf16x8 b[4];
#pragma unroll
          for (int nt = 0; nt < 4; ++nt) {
            int nl = nbl + nt * 16 + l16;
            int bo = nl * ROWB + (((ks * 32 + lq * 8) * 2) ^ ((nl & 7) << 4));
            b[nt] = *(const bf16x8*)(hrd + bo);
          }
#pragma unroll
          for (int mt = 0; mt < 4; ++mt)
#pragma unroll
            for (int nt = 0; nt < 4; ++nt)
              acc[mt][nt] = __builtin_amdgcn_mfma_f32_16x16x32_bf16(a[mt], b[nt], acc[mt][nt], 0, 0, 0);
        }
      }

      // cell update (in-lane: j == gate i,f,g,o); c==0 at t=0 gives T0 math
#pragma unroll
      for (int mt = 0; mt < 4; ++mt) {
        int fe = rs * 16 + mt * 4 + lq;
        const int h2 = mt >> 1, q4 = (mt & 1) * 4;
#pragma unroll
        for (int nt = 0; nt < 4; ++nt) {
          int nl = nbl + nt * 16 + l16;
          float pi = acc[mt][nt][0] + bf2f(xwall[i][nt][h2][q4 + 0]);
          float pf = acc[mt][nt][1] + bf2f(xwall[i][nt][h2][q4 + 1]);
          float pg = acc[mt][nt][2] + bf2f(xwall[i][nt][h2][q4 + 2]);
          float po = acc[mt][nt][3] + bf2f(xwall[i][nt][h2][q4 + 3]);
          float cn = sigm(pf) * c[i][mt][nt] + sigm(pi) * tanhfast(pg);
          c[i][mt][nt] = cn;
          float hn = sigm(po) * tanhfast(cn);
          int bo = nl * ROWB + ((fe * 2) ^ ((nl & 7) << 4));
          *(u16*)(hwr + bo) = f2bf(hn);
        }
      }
    }
    __syncthreads();
  }

  // final h (DEG even -> hbuf[0]) -> global, coalesced 16B chunks
  const char* hf = (const char*)hbuf[0];
  constexpr int CPN = F / 8;
  for (int idx = tid; idx < NT * CPN; idx += 512) {
    int n = idx / CPN, fg = idx % CPN;
    int bo = n * ROWB + ((fg * 16) ^ ((n & 7) << 4));
    u16x8 v = *(const u16x8*)(hf + bo);
    *(u16x8*)(hout + (size_t)(nodeg + n) * F + fg * 8) = v;
  }
}

// ---- mean-pool per graph + classifier -----------------------------------
__global__ void k_pool(const u16* __restrict__ h2, const float* __restrict__ Wc,
                       const float* __restrict__ bc, float* __restrict__ out) {
  __shared__ float hg[HIDF];
  int g = blockIdx.x;
  int tid = threadIdx.x;
  float s = 0.0f;
  for (int i = 0; i < NPG; ++i) s += bf2f(h2[(size_t)(g * NPG + i) * HIDF + tid]);
  hg[tid] = s * (1.0f / NPG);
  __syncthreads();
  if (tid < OUT_F) {
    float o = bc[tid];
    for (int fe = 0; fe < HIDF; ++fe) o += hg[fe] * Wc[tid * HIDF + fe];
    out[g * OUT_F + tid] = o;
  }
}

// ---- launch -------------------------------------------------------------
extern "C" void kernel_launch(void* const* d_in, const int* in_sizes, int n_in,
                              void* d_out, int out_size, void* d_ws, size_t ws_size,
                              hipStream_t stream) {
  const float* x   = (const float*)d_in[0];
  const int*   nbr = (const int*)d_in[1];
  const float* Wi1 = (const float*)d_in[2];
  const float* Wh1 = (const float*)d_in[3];
  const float* bi1 = (const float*)d_in[4];
  const float* bh1 = (const float*)d_in[5];
  const float* Ws1 = (const float*)d_in[6];
  const float* Wn1 = (const float*)d_in[7];
  const float* b1  = (const float*)d_in[8];
  const float* Wi2 = (const float*)d_in[9];
  const float* Wh2 = (const float*)d_in[10];
  const float* bi2 = (const float*)d_in[11];
  const float* bh2 = (const float*)d_in[12];
  const float* Ws2 = (const float*)d_in[13];
  const float* Wn2 = (const float*)d_in[14];
  const float* b2  = (const float*)d_in[15];
  const float* Wc  = (const float*)d_in[16];
  const float* bc  = (const float*)d_in[17];
  float* out = (float*)d_out;

  char* ws = (char*)d_ws;
  const size_t MB = 1u << 20;
  // layout (no per-step h/c buffers anymore):
  u16*   x16  = (u16*)(ws + 0);          //  8 MB, dead after XW1/XS1 gemms
  u16*   h1o  = x16;                     //  8 MB (over x16, dead by then)
  u16*   XW1  = (u16*)(ws + 8 * MB);     // 32 MB
  u16*   XS1  = (u16*)(ws + 40 * MB);    // 16 MB; X2 in-place by comb1
  u16*   X2   = XS1;
  u16*   XW2  = (u16*)(ws + 56 * MB);    // 64 MB
  u16*   XS2  = (u16*)(ws + 120 * MB);   // 16 MB; h2o in-place by comb2
  u16*   h2o  = XS2;
  u16*   h2f  = (u16*)(ws + 136 * MB);   // 16 MB
  char* wr = ws + 152 * MB;
  size_t off = 0;
  auto alloc = [&](size_t bytes) { void* p = wr + off; off += (bytes + 255) & ~(size_t)255; return p; };
  u16*   Wip1 = (u16*)alloc(512 * 128 * 2);
  u16*   Whp1 = (u16*)alloc(512 * 128 * 2);
  float* bwp1 = (float*)alloc(512 * 4);
  u16*   Bs1  = (u16*)alloc(256 * 128 * 2);
  u16*   Bn1  = (u16*)alloc(256 * 128 * 2);
  u16*   Wip2 = (u16*)alloc(1024 * 256 * 2);
  u16*   Whp2 = (u16*)alloc(1024 * 256 * 2);
  float* bwp2 = (float*)alloc(1024 * 4);
  u16*   Bs2  = (u16*)alloc(256 * 256 * 2);
  u16*   Bn2  = (u16*)alloc(256 * 256 * 2);

  k_prep_x<<<dim3(N_NODES * IN_F / 4 / 256), dim3(256), 0, stream>>>(x, x16, N_NODES * IN_F / 4);
  k_prep_wg<<<dim3(256), dim3(256), 0, stream>>>(Wi1, Wh1, bi1, bh1, Wip1, Whp1, bwp1, IN_F);
  k_prep_wg<<<dim3(1024), dim3(256), 0, stream>>>(Wi2, Wh2, bi2, bh2, Wip2, Whp2, bwp2, HIDF);
  k_prep_cast<<<dim3(128), dim3(256), 0, stream>>>(Ws1, Wn1, Bs1, Bn1, 256 * 128);
  k_prep_cast<<<dim3(256), dim3(256), 0, stream>>>(Ws2, Wn2, Bs2, Bn2, 256 * 256);

  // ---- layer 1 ----
  k_gemm<128, 512><<<dim3(N_NODES / 64, 4), dim3(256), 0, stream>>>(x16, Wip1, bwp1, XW1);
  k_gemm<128, 256><<<dim3(N_NODES / 64, 2), dim3(256), 0, stream>>>(x16, Bs1, b1, XS1);
  k_layer<IN_F><<<dim3(N_NODES / 128), dim3(512), 0, stream>>>(XW1, Whp1, nbr, h1o);
  k_comb<128><<<dim3(N_NODES / 64, 2), dim3(256), 0, stream>>>(h1o, Bn1, XS1, X2);

  // ---- layer 2 ----
  k_gemm<256, 1024><<<dim3(N_NODES / 64, 8), dim3(256), 0, stream>>>(X2, Wip2, bwp2, XW2);
  k_gemm<256, 256><<<dim3(N_NODES / 64, 2), dim3(256), 0, stream>>>(X2, Bs2, b2, XS2);
  k_layer<HIDF><<<dim3(N_NODES / 128), dim3(512), 0, stream>>>(XW2, Whp2, nbr, h2f);
  k_comb<256><<<dim3(N_NODES / 64, 2), dim3(256), 0, stream>>>(h2f, Bn2, XS2, h2o);

  k_pool<<<dim3(N_GRAPHS), dim3(256), 0, stream>>>(h2o, Wc, bc, out);
}

// Round 16
// 1282.673 us; speedup vs baseline: 1.2486x; 1.2486x over previous
//
#include <hip/hip_runtime.h>

#define N_NODES 32768
#define DEG 16
#define IN_F 128
#define HIDF 256
#define N_GRAPHS 256
#define NPG 128
#define OUT_F 16

typedef unsigned short u16;
typedef unsigned int u32;
typedef __bf16 bf16x8 __attribute__((ext_vector_type(8)));
typedef float f32x4 __attribute__((ext_vector_type(4)));
typedef u16 u16x4 __attribute__((ext_vector_type(4)));
typedef u16 u16x8 __attribute__((ext_vector_type(8)));

__device__ __forceinline__ u16 f2bf(float f) {
  union { float f; unsigned u; } v; v.f = f;
  return (u16)((v.u + 0x7FFFu + ((v.u >> 16) & 1u)) >> 16);
}
__device__ __forceinline__ float bf2f(u16 b) {
  union { unsigned u; float f; } v; v.u = ((unsigned)b) << 16;
  return v.f;
}
__device__ __forceinline__ float sigm(float x) { return 1.0f / (1.0f + __expf(-x)); }
__device__ __forceinline__ float tanhfast(float x) {
  float e = __expf(2.0f * x);
  return (e - 1.0f) / (e + 1.0f);
}

// ---- prep kernels -------------------------------------------------------

__global__ void k_prep_x(const float* __restrict__ x, u16* __restrict__ out, int n4) {
  int i = blockIdx.x * blockDim.x + threadIdx.x;
  if (i < n4) {
    float4 v = ((const float4*)x)[i];
    ushort4 o;
    o.x = f2bf(v.x); o.y = f2bf(v.y); o.z = f2bf(v.z); o.w = f2bf(v.w);
    ((ushort4*)out)[i] = o;
  }
}

// Whp: gate-interleaved rows p = fe*4 + gate (MFMA C-fragment j == gate).
// Wip/bwp: additionally lq-major WITHIN each 64-row slice, so a k_step
// thread's 16 gather values (4 fe x 4 gates) are 32B contiguous:
//   new local q = lq*16 + mt*4 + gate  <->  old local = mt*16 + lq*4 + gate
__global__ void k_prep_wg(const float* __restrict__ Wi, const float* __restrict__ Wh,
                          const float* __restrict__ bi, const float* __restrict__ bh,
                          u16* __restrict__ Wip, u16* __restrict__ Whp,
                          float* __restrict__ bwp, int F) {
  int total = 4 * F * F;
  for (int idx = blockIdx.x * blockDim.x + threadIdx.x; idx < total;
       idx += gridDim.x * blockDim.x) {
    int p = idx / F, k = idx % F;
    {  // Whp: old order
      int fe = p >> 2, g = p & 3;
      int orig = g * F + fe;
      Whp[idx] = f2bf(Wh[orig * F + k]);
    }
    {  // Wip + bwp: lq-major slice order
      int base = p & ~63, local = p & 63;
      int lq = local >> 4, mt = (local >> 2) & 3, gate = local & 3;
      int oldp = base + mt * 16 + lq * 4 + gate;
      int fe = oldp >> 2, g = oldp & 3;
      int orig = g * F + fe;
      Wip[idx] = f2bf(Wi[orig * F + k]);
      if (k == 0) bwp[p] = bi[orig] + bh[orig];
    }
  }
}

__global__ void k_prep_cast(const float* __restrict__ Ws, const float* __restrict__ Wn,
                            u16* __restrict__ Bs, u16* __restrict__ Bn, int n) {
  int i = blockIdx.x * blockDim.x + threadIdx.x;
  if (i < n) { Bs[i] = f2bf(Ws[i]); Bn[i] = f2bf(Wn[i]); }
}

// ---- dense GEMM: C[M][NC] = bf16(A[M][K] @ B[NC][K]^T + bias) ------------
template <int K, int NC>
__launch_bounds__(256, 4)
__global__ void k_gemm(const u16* __restrict__ A, const u16* __restrict__ B,
                       const float* __restrict__ bias, u16* __restrict__ C) {
  constexpr int ROWB = 2 * K;
  __shared__ u16 lds[64 * K];
  char* ldsb = (char*)lds;
  const int tid = threadIdx.x;
  const int w = tid >> 6;
  const int lane = tid & 63;
  const int l16 = lane & 15, lq = lane >> 4;
  const int row0 = blockIdx.x * 64;
  const int col0 = blockIdx.y * 128;

  constexpr int CH = K / 8;
  constexpr int RPI = 256 / CH;
#pragma unroll
  for (int it = 0; it < 64 / RPI; ++it) {
    int r = tid / CH + it * RPI;
    int ch = tid % CH;
    bf16x8 v = *(const bf16x8*)(A + (size_t)(row0 + r) * K + ch * 8);
    int bo = r * ROWB + ((ch * 16) ^ ((r & 7) << 4));
    *(bf16x8*)(ldsb + bo) = v;
  }
  __syncthreads();

  f32x4 acc[4][2];
#pragma unroll
  for (int mt = 0; mt < 4; ++mt)
#pragma unroll
    for (int nt = 0; nt < 2; ++nt)
#pragma unroll
      for (int j = 0; j < 4; ++j) acc[mt][nt][j] = 0.f;

  for (int ks = 0; ks < K / 32; ++ks) {
    bf16x8 a[4];
#pragma unroll
    for (int mt = 0; mt < 4; ++mt) {
      int r = mt * 16 + l16;
      int bo = r * ROWB + (((ks * 32 + lq * 8) * 2) ^ ((r & 7) << 4));
      a[mt] = *(const bf16x8*)(ldsb + bo);
    }
#pragma unroll
    for (int nt = 0; nt < 2; ++nt) {
      int coln = col0 + w * 32 + nt * 16 + l16;
      bf16x8 b = *(const bf16x8*)(B + (size_t)coln * K + ks * 32 + lq * 8);
#pragma unroll
      for (int mt = 0; mt < 4; ++mt)
        acc[mt][nt] = __builtin_amdgcn_mfma_f32_16x16x32_bf16(a[mt], b, acc[mt][nt], 0, 0, 0);
    }
  }
#pragma unroll
  for (int mt = 0; mt < 4; ++mt)
#pragma unroll
    for (int nt = 0; nt < 2; ++nt) {
      int coln = col0 + w * 32 + nt * 16 + l16;
      float bb = bias[coln];
#pragma unroll
      for (int j = 0; j < 4; ++j) {
        int r = row0 + mt * 16 + lq * 4 + j;
        C[(size_t)r * NC + coln] = f2bf(acc[mt][nt][j] + bb);
      }
    }
}

// ---- combine GEMM: C[r][coln] = relu_bf16(XS[r][coln] + A[r]@B[coln]) ----
template <int K>
__launch_bounds__(256, 4)
__global__ void k_comb(const u16* __restrict__ A, const u16* __restrict__ B,
                       const u16* __restrict__ XS, u16* __restrict__ C) {
  constexpr int ROWB = 2 * K;
  __shared__ u16 lds[64 * K];
  char* ldsb = (char*)lds;
  const int tid = threadIdx.x;
  const int w = tid >> 6;
  const int lane = tid & 63;
  const int l16 = lane & 15, lq = lane >> 4;
  const int row0 = blockIdx.x * 64;
  const int col0 = blockIdx.y * 128;

  constexpr int CH = K / 8;
  constexpr int RPI = 256 / CH;
#pragma unroll
  for (int it = 0; it < 64 / RPI; ++it) {
    int r = tid / CH + it * RPI;
    int ch = tid % CH;
    bf16x8 v = *(const bf16x8*)(A + (size_t)(row0 + r) * K + ch * 8);
    int bo = r * ROWB + ((ch * 16) ^ ((r & 7) << 4));
    *(bf16x8*)(ldsb + bo) = v;
  }
  __syncthreads();

  f32x4 acc[4][2];
#pragma unroll
  for (int mt = 0; mt < 4; ++mt)
#pragma unroll
    for (int nt = 0; nt < 2; ++nt)
#pragma unroll
      for (int j = 0; j < 4; ++j) acc[mt][nt][j] = 0.f;

  for (int ks = 0; ks < K / 32; ++ks) {
    bf16x8 a[4];
#pragma unroll
    for (int mt = 0; mt < 4; ++mt) {
      int r = mt * 16 + l16;
      int bo = r * ROWB + (((ks * 32 + lq * 8) * 2) ^ ((r & 7) << 4));
      a[mt] = *(const bf16x8*)(ldsb + bo);
    }
#pragma unroll
    for (int nt = 0; nt < 2; ++nt) {
      int coln = col0 + w * 32 + nt * 16 + l16;
      bf16x8 b = *(const bf16x8*)(B + (size_t)coln * K + ks * 32 + lq * 8);
#pragma unroll
      for (int mt = 0; mt < 4; ++mt)
        acc[mt][nt] = __builtin_amdgcn_mfma_f32_16x16x32_bf16(a[mt], b, acc[mt][nt], 0, 0, 0);
    }
  }
#pragma unroll
  for (int mt = 0; mt < 4; ++mt)
#pragma unroll
    for (int nt = 0; nt < 2; ++nt) {
      int coln = col0 + w * 32 + nt * 16 + l16;
#pragma unroll
      for (int j = 0; j < 4; ++j) {
        int r = row0 + mt * 16 + lq * 4 + j;
        float v = acc[mt][nt][j] + bf2f(XS[(size_t)r * HIDF + coln]);
        C[(size_t)r * HIDF + coln] = f2bf(fmaxf(v, 0.f));
      }
    }
}

// ---- one LSTM step as a dense GEMM + fused cell update -------------------
// Session-best configuration (round 11, 57.4us/step): wave-tile 64 rows x
// 32 nodes (BN=256/block, 512 thr / 8 waves), LDS-staged Whp (swizzled),
// lq-major XW gather (2x16B per thread per node, 4 lq lanes cover one 64B
// line), c state bf16 [F][N], XCD-bijective swizzle, 2 barriers.
template <int F, bool T0>
__launch_bounds__(512, 4)
__global__ void k_step(const u16* __restrict__ hprev, // [N][F] node-major
                       const u16* __restrict__ XW,    // [N][4F] lq-major slices
                       const u16* __restrict__ Whp,   // [4F][F] old gate-order
                       const int* __restrict__ nbr,   // [N][DEG]
                       int t,
                       u16* __restrict__ cT,          // [F][N] bf16
                       u16* __restrict__ hnext) {     // [N][F] node-major
  constexpr int ROWB = 2 * F;
  constexpr int KS = F / 32;
  constexpr int RBN = F / 16;   // gridDim.x
  __shared__ __align__(16) u16 Alds[64 * F];
  __shared__ __align__(16) u16 tl[256 * 24];
  char* ldsb = (char*)Alds;
  const int tid = threadIdx.x;
  const int w = tid >> 6;
  const int lane = tid & 63;
  const int l16 = lane & 15, lq = lane >> 4;

  // XCD-bijective swizzle: all RBN row-blocks of node-group g share an XCD.
  const int p = blockIdx.x + RBN * blockIdx.y;
  const int s = p >> 3;
  const int rb = s % RBN;
  const int g = (p & 7) + 8 * (s / RBN);

  const int row0 = rb * 64;
  const int col0 = g * 256;
  const int feb = row0 >> 2;
  const int n0 = col0 + w * 32 + l16;
  const int n1 = n0 + 16;

  const int nb0 = nbr[(size_t)n0 * DEG + t];
  const int nb1 = nbr[(size_t)n1 * DEG + t];

  if constexpr (!T0) {
    constexpr int CH = F / 8;
    constexpr int RPI = 512 / CH;
#pragma unroll
    for (int it = 0; it < 64 / RPI; ++it) {
      int r = tid / CH + it * RPI;
      int ch = tid % CH;
      bf16x8 v = *(const bf16x8*)(Whp + (size_t)(row0 + r) * F + ch * 8);
      int bo = r * ROWB + ((ch * 16) ^ ((r & 7) << 4));
      *(bf16x8*)(ldsb + bo) = v;
    }
  }

  // XW gather: per node, this thread's 16 values are 32B contiguous
  u16x8 xwv[2][2];
  {
    const u16* b0 = XW + (size_t)nb0 * (4 * F) + row0 + lq * 16;
    const u16* b1 = XW + (size_t)nb1 * (4 * F) + row0 + lq * 16;
    xwv[0][0] = *(const u16x8*)(b0);
    xwv[0][1] = *(const u16x8*)(b0 + 8);
    xwv[1][0] = *(const u16x8*)(b1);
    xwv[1][1] = *(const u16x8*)(b1 + 8);
  }

  float cold[4][2];
  if constexpr (!T0) {
#pragma unroll
    for (int mt = 0; mt < 4; ++mt) {
      cold[mt][0] = bf2f(cT[(size_t)(feb + mt * 4 + lq) * N_NODES + n0]);
      cold[mt][1] = bf2f(cT[(size_t)(feb + mt * 4 + lq) * N_NODES + n1]);
    }
  }

  f32x4 acc[4][2];
#pragma unroll
  for (int mt = 0; mt < 4; ++mt)
#pragma unroll
    for (int nt = 0; nt < 2; ++nt)
#pragma unroll
      for (int j = 0; j < 4; ++j) acc[mt][nt][j] = 0.f;

  if constexpr (!T0) {
    __syncthreads();
    const u16* hb0 = hprev + (size_t)n0 * F + lq * 8;
    const u16* hb1 = hprev + (size_t)n1 * F + lq * 8;
#pragma unroll
    for (int ks = 0; ks < KS; ++ks) {
      bf16x8 b0 = *(const bf16x8*)(hb0 + ks * 32);
      bf16x8 b1 = *(const bf16x8*)(hb1 + ks * 32);
      bf16x8 a[4];
#pragma unroll
      for (int mt = 0; mt < 4; ++mt) {
        int r = mt * 16 + l16;
        int bo = r * ROWB + (((ks * 32 + lq * 8) * 2) ^ ((r & 7) << 4));
        a[mt] = *(const bf16x8*)(ldsb + bo);
      }
#pragma unroll
      for (int mt = 0; mt < 4; ++mt) {
        acc[mt][0] = __builtin_amdgcn_mfma_f32_16x16x32_bf16(a[mt], b0, acc[mt][0], 0, 0, 0);
        acc[mt][1] = __builtin_amdgcn_mfma_f32_16x16x32_bf16(a[mt], b1, acc[mt][1], 0, 0, 0);
      }
    }
  }

  // fused LSTM cell update (in-lane: j = gate index i,f,g,o)
#pragma unroll
  for (int mt = 0; mt < 4; ++mt) {
    int fe = feb + mt * 4 + lq;
#pragma unroll
    for (int nt = 0; nt < 2; ++nt) {
      int n = nt ? n1 : n0;
      float pi, pf, pg, po;
      if (mt < 2) {
        pi = acc[mt][nt][0] + bf2f(xwv[nt][0][(mt & 1) * 4 + 0]);
        pf = acc[mt][nt][1] + bf2f(xwv[nt][0][(mt & 1) * 4 + 1]);
        pg = acc[mt][nt][2] + bf2f(xwv[nt][0][(mt & 1) * 4 + 2]);
        po = acc[mt][nt][3] + bf2f(xwv[nt][0][(mt & 1) * 4 + 3]);
      } else {
        pi = acc[mt][nt][0] + bf2f(xwv[nt][1][(mt & 1) * 4 + 0]);
        pf = acc[mt][nt][1] + bf2f(xwv[nt][1][(mt & 1) * 4 + 1]);
        pg = acc[mt][nt][2] + bf2f(xwv[nt][1][(mt & 1) * 4 + 2]);
        po = acc[mt][nt][3] + bf2f(xwv[nt][1][(mt & 1) * 4 + 3]);
      }
      float cn;
      if constexpr (T0) cn = sigm(pi) * tanhfast(pg);
      else              cn = sigm(pf) * cold[mt][nt] + sigm(pi) * tanhfast(pg);
      float hn = sigm(po) * tanhfast(cn);
      cT[(size_t)fe * N_NODES + n] = f2bf(cn);
      tl[(w * 32 + nt * 16 + l16) * 24 + mt * 4 + lq] = f2bf(hn);
    }
  }
  __syncthreads();
  {
    int nloc = tid >> 1, q = tid & 1;
    u16x8 v = *(const u16x8*)&tl[nloc * 24 + q * 8];
    *(u16x8*)(hnext + (size_t)(col0 + nloc) * F + feb + q * 8) = v;
  }
}

// ---- mean-pool per graph + classifier -----------------------------------
__global__ void k_pool(const u16* __restrict__ h2, const float* __restrict__ Wc,
                       const float* __restrict__ bc, float* __restrict__ out) {
  __shared__ float hg[HIDF];
  int g = blockIdx.x;
  int tid = threadIdx.x;
  float s = 0.0f;
  for (int i = 0; i < NPG; ++i) s += bf2f(h2[(size_t)(g * NPG + i) * HIDF + tid]);
  hg[tid] = s * (1.0f / NPG);
  __syncthreads();
  if (tid < OUT_F) {
    float o = bc[tid];
    for (int fe = 0; fe < HIDF; ++fe) o += hg[fe] * Wc[tid * HIDF + fe];
    out[g * OUT_F + tid] = o;
  }
}

// ---- launch -------------------------------------------------------------
extern "C" void kernel_launch(void* const* d_in, const int* in_sizes, int n_in,
                              void* d_out, int out_size, void* d_ws, size_t ws_size,
                              hipStream_t stream) {
  const float* x   = (const float*)d_in[0];
  const int*   nbr = (const int*)d_in[1];
  const float* Wi1 = (const float*)d_in[2];
  const float* Wh1 = (const float*)d_in[3];
  const float* bi1 = (const float*)d_in[4];
  const float* bh1 = (const float*)d_in[5];
  const float* Ws1 = (const float*)d_in[6];
  const float* Wn1 = (const float*)d_in[7];
  const float* b1  = (const float*)d_in[8];
  const float* Wi2 = (const float*)d_in[9];
  const float* Wh2 = (const float*)d_in[10];
  const float* bi2 = (const float*)d_in[11];
  const float* bh2 = (const float*)d_in[12];
  const float* Ws2 = (const float*)d_in[13];
  const float* Wn2 = (const float*)d_in[14];
  const float* b2  = (const float*)d_in[15];
  const float* Wc  = (const float*)d_in[16];
  const float* bc  = (const float*)d_in[17];
  float* out = (float*)d_out;

  char* ws = (char*)d_ws;
  const size_t MB = 1u << 20;
  // liveness-packed (high-water 144 MB + weights):
  u16*   x16 = (u16*)(ws + 0);          //  8 MB, dead after XW1/XS1 gemms
  u16*   XW1 = (u16*)(ws + 8 * MB);     // 32 MB, dead after layer-1 steps
  u16*   XS1 = (u16*)(ws + 40 * MB);    // 16 MB; X2 in-place by comb1
  u16*   X2  = XS1;
  u16*   hA1 = (u16*)(ws + 56 * MB);    //  8 MB
  u16*   hB1 = (u16*)(ws + 64 * MB);    //  8 MB
  u16*   c1  = (u16*)(ws + 72 * MB);    //  8 MB bf16 [128][N]
  u16*   XW2 = (u16*)(ws + 80 * MB);    // 64 MB
  u16*   XS2 = (u16*)(ws + 0);          // 16 MB (over x16+XW1-head, dead); h2o in place
  u16*   h2o = XS2;
  u16*   hA2 = (u16*)(ws + 16 * MB);    // 16 MB (over XW1, dead)
  u16*   hB2 = (u16*)(ws + 32 * MB);    // 16 MB (over XW1-tail + X2, dead by t=1)
  u16*   c2  = (u16*)(ws + 56 * MB);    // 16 MB bf16 (over hA1/hB1/c1, dead after comb1)
  char* wr = ws + 144 * MB;
  size_t off = 0;
  auto alloc = [&](size_t bytes) { void* p = wr + off; off += (bytes + 255) & ~(size_t)255; return p; };
  u16*   Wip1 = (u16*)alloc(512 * 128 * 2);
  u16*   Whp1 = (u16*)alloc(512 * 128 * 2);
  float* bwp1 = (float*)alloc(512 * 4);
  u16*   Bs1  = (u16*)alloc(256 * 128 * 2);
  u16*   Bn1  = (u16*)alloc(256 * 128 * 2);
  u16*   Wip2 = (u16*)alloc(1024 * 256 * 2);
  u16*   Whp2 = (u16*)alloc(1024 * 256 * 2);
  float* bwp2 = (float*)alloc(1024 * 4);
  u16*   Bs2  = (u16*)alloc(256 * 256 * 2);
  u16*   Bn2  = (u16*)alloc(256 * 256 * 2);

  k_prep_x<<<dim3(N_NODES * IN_F / 4 / 256), dim3(256), 0, stream>>>(x, x16, N_NODES * IN_F / 4);
  k_prep_wg<<<dim3(256), dim3(256), 0, stream>>>(Wi1, Wh1, bi1, bh1, Wip1, Whp1, bwp1, IN_F);
  k_prep_wg<<<dim3(1024), dim3(256), 0, stream>>>(Wi2, Wh2, bi2, bh2, Wip2, Whp2, bwp2, HIDF);
  k_prep_cast<<<dim3(128), dim3(256), 0, stream>>>(Ws1, Wn1, Bs1, Bn1, 256 * 128);
  k_prep_cast<<<dim3(256), dim3(256), 0, stream>>>(Ws2, Wn2, Bs2, Bn2, 256 * 256);

  // ---- layer 1 ----  (RBN = 8, node-groups = 128)
  k_gemm<128, 512><<<dim3(N_NODES / 64, 4), dim3(256), 0, stream>>>(x16, Wip1, bwp1, XW1);
  k_gemm<128, 256><<<dim3(N_NODES / 64, 2), dim3(256), 0, stream>>>(x16, Bs1, b1, XS1);
  {
    k_step<IN_F, true><<<dim3(8, N_NODES / 256), dim3(512), 0, stream>>>(
        hA1, XW1, Whp1, nbr, 0, c1, hA1);
    u16* hc = hA1; u16* hn = hB1;
    for (int t = 1; t < DEG; ++t) {
      k_step<IN_F, false><<<dim3(8, N_NODES / 256), dim3(512), 0, stream>>>(
          hc, XW1, Whp1, nbr, t, c1, hn);
      u16* tmp = hc; hc = hn; hn = tmp;
    }
    k_comb<128><<<dim3(N_NODES / 64, 2), dim3(256), 0, stream>>>(hc, Bn1, XS1, X2);
  }

  // ---- layer 2 ----  (RBN = 16, node-groups = 128)
  k_gemm<256, 1024><<<dim3(N_NODES / 64, 8), dim3(256), 0, stream>>>(X2, Wip2, bwp2, XW2);
  k_gemm<256, 256><<<dim3(N_NODES / 64, 2), dim3(256), 0, stream>>>(X2, Bs2, b2, XS2);
  {
    k_step<HIDF, true><<<dim3(16, N_NODES / 256), dim3(512), 0, stream>>>(
        hA2, XW2, Whp2, nbr, 0, c2, hA2);
    u16* hc = hA2; u16* hn = hB2;
    for (int t = 1; t < DEG; ++t) {
      k_step<HIDF, false><<<dim3(16, N_NODES / 256), dim3(512), 0, stream>>>(
          hc, XW2, Whp2, nbr, t, c2, hn);
      u16* tmp = hc; hc = hn; hn = tmp;
    }
    k_comb<256><<<dim3(N_NODES / 64, 2), dim3(256), 0, stream>>>(hc, Bn2, XS2, h2o);
  }

  k_pool<<<dim3(N_GRAPHS), dim3(256), 0, stream>>>(h2o, Wc, bc, out);
}

// Round 17
// 1160.986 us; speedup vs baseline: 1.3795x; 1.1048x over previous
//
#include <hip/hip_runtime.h>

#define N_NODES 32768
#define DEG 16
#define IN_F 128
#define HIDF 256
#define N_GRAPHS 256
#define NPG 128
#define OUT_F 16

typedef unsigned short u16;
typedef unsigned int u32;
typedef __bf16 bf16x8 __attribute__((ext_vector_type(8)));
typedef float f32x4 __attribute__((ext_vector_type(4)));
typedef u16 u16x4 __attribute__((ext_vector_type(4)));
typedef u16 u16x8 __attribute__((ext_vector_type(8)));

__device__ __forceinline__ u16 f2bf(float f) {
  union { float f; unsigned u; } v; v.f = f;
  return (u16)((v.u + 0x7FFFu + ((v.u >> 16) & 1u)) >> 16);
}
__device__ __forceinline__ float bf2f(u16 b) {
  union { unsigned u; float f; } v; v.u = ((unsigned)b) << 16;
  return v.f;
}
__device__ __forceinline__ float sigm(float x) { return 1.0f / (1.0f + __expf(-x)); }
__device__ __forceinline__ float tanhfast(float x) {
  float e = __expf(2.0f * x);
  return (e - 1.0f) / (e + 1.0f);
}

// ---- prep kernels -------------------------------------------------------

__global__ void k_prep_x(const float* __restrict__ x, u16* __restrict__ out, int n4) {
  int i = blockIdx.x * blockDim.x + threadIdx.x;
  if (i < n4) {
    float4 v = ((const float4*)x)[i];
    ushort4 o;
    o.x = f2bf(v.x); o.y = f2bf(v.y); o.z = f2bf(v.z); o.w = f2bf(v.w);
    ((ushort4*)out)[i] = o;
  }
}

// Whp: gate-interleaved rows p = fe*4 + gate (MFMA C-fragment j == gate).
// Wip/bwp: additionally lq-major WITHIN each 64-row slice, so a gather
// thread's 16 values (4 fe x 4 gates) are 32B contiguous:
//   new local q = lq*16 + mt*4 + gate  <->  old local = mt*16 + lq*4 + gate
__global__ void k_prep_wg(const float* __restrict__ Wi, const float* __restrict__ Wh,
                          const float* __restrict__ bi, const float* __restrict__ bh,
                          u16* __restrict__ Wip, u16* __restrict__ Whp,
                          float* __restrict__ bwp, int F) {
  int total = 4 * F * F;
  for (int idx = blockIdx.x * blockDim.x + threadIdx.x; idx < total;
       idx += gridDim.x * blockDim.x) {
    int p = idx / F, k = idx % F;
    {  // Whp: old order
      int fe = p >> 2, g = p & 3;
      int orig = g * F + fe;
      Whp[idx] = f2bf(Wh[orig * F + k]);
    }
    {  // Wip + bwp: lq-major slice order
      int base = p & ~63, local = p & 63;
      int lq = local >> 4, mt = (local >> 2) & 3, gate = local & 3;
      int oldp = base + mt * 16 + lq * 4 + gate;
      int fe = oldp >> 2, g = oldp & 3;
      int orig = g * F + fe;
      Wip[idx] = f2bf(Wi[orig * F + k]);
      if (k == 0) bwp[p] = bi[orig] + bh[orig];
    }
  }
}

__global__ void k_prep_cast(const float* __restrict__ Ws, const float* __restrict__ Wn,
                            u16* __restrict__ Bs, u16* __restrict__ Bn, int n) {
  int i = blockIdx.x * blockDim.x + threadIdx.x;
  if (i < n) { Bs[i] = f2bf(Ws[i]); Bn[i] = f2bf(Wn[i]); }
}

// ---- dense GEMM: C[M][NC] = bf16(A[M][K] @ B[NC][K]^T + bias) ------------
template <int K, int NC>
__launch_bounds__(256, 4)
__global__ void k_gemm(const u16* __restrict__ A, const u16* __restrict__ B,
                       const float* __restrict__ bias, u16* __restrict__ C) {
  constexpr int ROWB = 2 * K;
  __shared__ u16 lds[64 * K];
  char* ldsb = (char*)lds;
  const int tid = threadIdx.x;
  const int w = tid >> 6;
  const int lane = tid & 63;
  const int l16 = lane & 15, lq = lane >> 4;
  const int row0 = blockIdx.x * 64;
  const int col0 = blockIdx.y * 128;

  constexpr int CH = K / 8;
  constexpr int RPI = 256 / CH;
#pragma unroll
  for (int it = 0; it < 64 / RPI; ++it) {
    int r = tid / CH + it * RPI;
    int ch = tid % CH;
    bf16x8 v = *(const bf16x8*)(A + (size_t)(row0 + r) * K + ch * 8);
    int bo = r * ROWB + ((ch * 16) ^ ((r & 7) << 4));
    *(bf16x8*)(ldsb + bo) = v;
  }
  __syncthreads();

  f32x4 acc[4][2];
#pragma unroll
  for (int mt = 0; mt < 4; ++mt)
#pragma unroll
    for (int nt = 0; nt < 2; ++nt)
#pragma unroll
      for (int j = 0; j < 4; ++j) acc[mt][nt][j] = 0.f;

  for (int ks = 0; ks < K / 32; ++ks) {
    bf16x8 a[4];
#pragma unroll
    for (int mt = 0; mt < 4; ++mt) {
      int r = mt * 16 + l16;
      int bo = r * ROWB + (((ks * 32 + lq * 8) * 2) ^ ((r & 7) << 4));
      a[mt] = *(const bf16x8*)(ldsb + bo);
    }
#pragma unroll
    for (int nt = 0; nt < 2; ++nt) {
      int coln = col0 + w * 32 + nt * 16 + l16;
      bf16x8 b = *(const bf16x8*)(B + (size_t)coln * K + ks * 32 + lq * 8);
#pragma unroll
      for (int mt = 0; mt < 4; ++mt)
        acc[mt][nt] = __builtin_amdgcn_mfma_f32_16x16x32_bf16(a[mt], b, acc[mt][nt], 0, 0, 0);
    }
  }
#pragma unroll
  for (int mt = 0; mt < 4; ++mt)
#pragma unroll
    for (int nt = 0; nt < 2; ++nt) {
      int coln = col0 + w * 32 + nt * 16 + l16;
      float bb = bias[coln];
#pragma unroll
      for (int j = 0; j < 4; ++j) {
        int r = row0 + mt * 16 + lq * 4 + j;
        C[(size_t)r * NC + coln] = f2bf(acc[mt][nt][j] + bb);
      }
    }
}

// ---- combine GEMM: C[r][coln] = relu_bf16(XS[r][coln] + A[r]@B[coln]) ----
template <int K>
__launch_bounds__(256, 4)
__global__ void k_comb(const u16* __restrict__ A, const u16* __restrict__ B,
                       const u16* __restrict__ XS, u16* __restrict__ C) {
  constexpr int ROWB = 2 * K;
  __shared__ u16 lds[64 * K];
  char* ldsb = (char*)lds;
  const int tid = threadIdx.x;
  const int w = tid >> 6;
  const int lane = tid & 63;
  const int l16 = lane & 15, lq = lane >> 4;
  const int row0 = blockIdx.x * 64;
  const int col0 = blockIdx.y * 128;

  constexpr int CH = K / 8;
  constexpr int RPI = 256 / CH;
#pragma unroll
  for (int it = 0; it < 64 / RPI; ++it) {
    int r = tid / CH + it * RPI;
    int ch = tid % CH;
    bf16x8 v = *(const bf16x8*)(A + (size_t)(row0 + r) * K + ch * 8);
    int bo = r * ROWB + ((ch * 16) ^ ((r & 7) << 4));
    *(bf16x8*)(ldsb + bo) = v;
  }
  __syncthreads();

  f32x4 acc[4][2];
#pragma unroll
  for (int mt = 0; mt < 4; ++mt)
#pragma unroll
    for (int nt = 0; nt < 2; ++nt)
#pragma unroll
      for (int j = 0; j < 4; ++j) acc[mt][nt][j] = 0.f;

  for (int ks = 0; ks < K / 32; ++ks) {
    bf16x8 a[4];
#pragma unroll
    for (int mt = 0; mt < 4; ++mt) {
      int r = mt * 16 + l16;
      int bo = r * ROWB + (((ks * 32 + lq * 8) * 2) ^ ((r & 7) << 4));
      a[mt] = *(const bf16x8*)(ldsb + bo);
    }
#pragma unroll
    for (int nt = 0; nt < 2; ++nt) {
      int coln = col0 + w * 32 + nt * 16 + l16;
      bf16x8 b = *(const bf16x8*)(B + (size_t)coln * K + ks * 32 + lq * 8);
#pragma unroll
      for (int mt = 0; mt < 4; ++mt)
        acc[mt][nt] = __builtin_amdgcn_mfma_f32_16x16x32_bf16(a[mt], b, acc[mt][nt], 0, 0, 0);
    }
  }
#pragma unroll
  for (int mt = 0; mt < 4; ++mt)
#pragma unroll
    for (int nt = 0; nt < 2; ++nt) {
      int coln = col0 + w * 32 + nt * 16 + l16;
#pragma unroll
      for (int j = 0; j < 4; ++j) {
        int r = row0 + mt * 16 + lq * 4 + j;
        float v = acc[mt][nt][j] + bf2f(XS[(size_t)r * HIDF + coln]);
        C[(size_t)r * HIDF + coln] = f2bf(fmaxf(v, 0.f));
      }
    }
}

// ---- whole-layer LSTM aggregation for F=128 (Whp fits in LDS) ------------
// Recurrence is PER-NODE (only XW is gathered), and for F=128 the FULL
// Whp (512x128 bf16 = 128KB) fits in LDS alongside h for 64 nodes (16KB):
// one block = 64 nodes x all 512 gate rows runs all DEG steps internally.
//  - W staged ONCE (swizzled), read all 16 steps,
//  - h in a single LDS buffer: read-phase barrier / write-phase barrier,
//  - c in registers (c[4][4] per thread),
//  - per-step memory traffic = the XW gather only (32B x 4 per thread).
// 8 waves, wave w owns rows [w*64, w*64+64) x all 64 nodes (ST=1):
// acc[4][4], xwv[4][2] -> ~170 VGPR under (512,2), no spill.
template <int F>
__launch_bounds__(512, 2)
__global__ void k_layer(const u16* __restrict__ XW,   // [N][4F] lq-major slices
                        const u16* __restrict__ Whp,  // [4F][F] gate-interleaved
                        const int* __restrict__ nbr,  // [N][DEG]
                        u16* __restrict__ hout) {     // [N][F]
  constexpr int NT = 64;
  constexpr int KS = F / 32;        // 4
  constexpr int ROWB = 2 * F;       // 256B per row (W slices and h)
  __shared__ __align__(16) u16 Wst[8 * 64 * F];  // 128 KB
  __shared__ __align__(16) u16 hbuf[NT * F];     // 16 KB
  __shared__ int snbrT[DEG * NT];                // 4 KB
  const int tid = threadIdx.x;
  const int w = tid >> 6;
  const int lane = tid & 63;
  const int l16 = lane & 15, lq = lane >> 4;
  const int nodeg = blockIdx.x * NT;
  const int row0 = w * 64;

  // stage ALL of Whp (4F x F) swizzled, once. 8192 16B-chunks / 512 thr.
#pragma unroll
  for (int it = 0; it < 16; ++it) {
    int idx = it * 512 + tid;
    int r = idx >> 4;                 // global gate-row 0..511
    int ch = idx & 15;                // 16B chunk within row
    bf16x8 v = *(const bf16x8*)(Whp + (size_t)r * F + ch * 8);
    int s = r >> 6, rr = r & 63;
    char* base = (char*)Wst + (size_t)s * (64 * ROWB);
    int bo = rr * ROWB + ((ch * 16) ^ ((rr & 7) << 4));
    *(bf16x8*)(base + bo) = v;
  }
  // transposed neighbor table
  for (int idx = tid; idx < DEG * NT; idx += 512) {
    int nl = idx / DEG, tt = idx % DEG;
    snbrT[tt * NT + nl] = nbr[(size_t)(nodeg + nl) * DEG + tt];
  }

  float c[4][4];
#pragma unroll
  for (int mt = 0; mt < 4; ++mt)
#pragma unroll
    for (int nt = 0; nt < 4; ++nt) c[mt][nt] = 0.f;

  __syncthreads();

  const char* wb = (const char*)Wst + (size_t)w * (64 * ROWB);
  const char* hb = (const char*)hbuf;
  char* hw = (char*)hbuf;

#pragma unroll 1
  for (int t = 0; t < DEG; ++t) {
    // gathers (global only, issued before the read barrier)
    u16x8 xwv[4][2];
#pragma unroll
    for (int nt = 0; nt < 4; ++nt) {
      int nb = snbrT[t * NT + nt * 16 + l16];
      const u16* bp = XW + (size_t)nb * (4 * F) + row0 + lq * 16;
      xwv[nt][0] = *(const u16x8*)(bp);
      xwv[nt][1] = *(const u16x8*)(bp + 8);
    }

    f32x4 acc[4][4];
#pragma unroll
    for (int mt = 0; mt < 4; ++mt)
#pragma unroll
      for (int nt = 0; nt < 4; ++nt)
#pragma unroll
        for (int j = 0; j < 4; ++j) acc[mt][nt][j] = 0.f;

    __syncthreads();  // (A) prior write phase complete -> h stable
    if (t > 0) {
#pragma unroll
      for (int ks = 0; ks < KS; ++ks) {
        bf16x8 a[4];
#pragma unroll
        for (int mt = 0; mt < 4; ++mt) {
          int rr = mt * 16 + l16;
          int bo = rr * ROWB + (((ks * 32 + lq * 8) * 2) ^ ((rr & 7) << 4));
          a[mt] = *(const bf16x8*)(wb + bo);
        }
        bf16x8 b[4];
#pragma unroll
        for (int nt = 0; nt < 4; ++nt) {
          int nl = nt * 16 + l16;
          int bo = nl * ROWB + (((ks * 32 + lq * 8) * 2) ^ ((nl & 7) << 4));
          b[nt] = *(const bf16x8*)(hb + bo);
        }
#pragma unroll
        for (int mt = 0; mt < 4; ++mt)
#pragma unroll
          for (int nt = 0; nt < 4; ++nt)
            acc[mt][nt] = __builtin_amdgcn_mfma_f32_16x16x32_bf16(a[mt], b[nt], acc[mt][nt], 0, 0, 0);
      }
    }
    __syncthreads();  // (B) all reads done -> safe to overwrite h

    // cell update (in-lane: j == gate i,f,g,o); c==0 at t=0 gives T0 math
#pragma unroll
    for (int mt = 0; mt < 4; ++mt) {
      int fe = w * 16 + mt * 4 + lq;
      const int h2 = mt >> 1, q4 = (mt & 1) * 4;
#pragma unroll
      for (int nt = 0; nt < 4; ++nt) {
        int nl = nt * 16 + l16;
        float pi = acc[mt][nt][0] + bf2f(xwv[nt][h2][q4 + 0]);
        float pf = acc[mt][nt][1] + bf2f(xwv[nt][h2][q4 + 1]);
        float pg = acc[mt][nt][2] + bf2f(xwv[nt][h2][q4 + 2]);
        float po = acc[mt][nt][3] + bf2f(xwv[nt][h2][q4 + 3]);
        float cn = sigm(pf) * c[mt][nt] + sigm(pi) * tanhfast(pg);
        c[mt][nt] = cn;
        float hn = sigm(po) * tanhfast(cn);
        int bo = nl * ROWB + ((fe * 2) ^ ((nl & 7) << 4));
        *(u16*)(hw + bo) = f2bf(hn);
      }
    }
  }
  __syncthreads();

  // final h -> global, unswizzled coalesced 16B chunks
  constexpr int CPN = F / 8;
  for (int idx = tid; idx < NT * CPN; idx += 512) {
    int nl = idx / CPN, fg = idx % CPN;
    int bo = nl * ROWB + ((fg * 16) ^ ((nl & 7) << 4));
    u16x8 v = *(const u16x8*)(hb + bo);
    *(u16x8*)(hout + (size_t)(nodeg + nl) * F + fg * 8) = v;
  }
}

// ---- one LSTM step as a dense GEMM + fused cell update (F=256 path) ------
// Session-best configuration (round 11, 57.0us/step): wave-tile 64 rows x
// 32 nodes (BN=256/block, 512 thr / 8 waves), LDS-staged Whp (swizzled),
// lq-major XW gather (2x16B per thread per node, 4 lq lanes cover one 64B
// line), c state bf16 [F][N], XCD-bijective swizzle, 2 barriers.
template <int F, bool T0>
__launch_bounds__(512, 4)
__global__ void k_step(const u16* __restrict__ hprev, // [N][F] node-major
                       const u16* __restrict__ XW,    // [N][4F] lq-major slices
                       const u16* __restrict__ Whp,   // [4F][F] old gate-order
                       const int* __restrict__ nbr,   // [N][DEG]
                       int t,
                       u16* __restrict__ cT,          // [F][N] bf16
                       u16* __restrict__ hnext) {     // [N][F] node-major
  constexpr int ROWB = 2 * F;
  constexpr int KS = F / 32;
  constexpr int RBN = F / 16;   // gridDim.x
  __shared__ __align__(16) u16 Alds[64 * F];
  __shared__ __align__(16) u16 tl[256 * 24];
  char* ldsb = (char*)Alds;
  const int tid = threadIdx.x;
  const int w = tid >> 6;
  const int lane = tid & 63;
  const int l16 = lane & 15, lq = lane >> 4;

  // XCD-bijective swizzle: all RBN row-blocks of node-group g share an XCD.
  const int p = blockIdx.x + RBN * blockIdx.y;
  const int s = p >> 3;
  const int rb = s % RBN;
  const int g = (p & 7) + 8 * (s / RBN);

  const int row0 = rb * 64;
  const int col0 = g * 256;
  const int feb = row0 >> 2;
  const int n0 = col0 + w * 32 + l16;
  const int n1 = n0 + 16;

  const int nb0 = nbr[(size_t)n0 * DEG + t];
  const int nb1 = nbr[(size_t)n1 * DEG + t];

  if constexpr (!T0) {
    constexpr int CH = F / 8;
    constexpr int RPI = 512 / CH;
#pragma unroll
    for (int it = 0; it < 64 / RPI; ++it) {
      int r = tid / CH + it * RPI;
      int ch = tid % CH;
      bf16x8 v = *(const bf16x8*)(Whp + (size_t)(row0 + r) * F + ch * 8);
      int bo = r * ROWB + ((ch * 16) ^ ((r & 7) << 4));
      *(bf16x8*)(ldsb + bo) = v;
    }
  }

  // XW gather: per node, this thread's 16 values are 32B contiguous
  u16x8 xwv[2][2];
  {
    const u16* b0 = XW + (size_t)nb0 * (4 * F) + row0 + lq * 16;
    const u16* b1 = XW + (size_t)nb1 * (4 * F) + row0 + lq * 16;
    xwv[0][0] = *(const u16x8*)(b0);
    xwv[0][1] = *(const u16x8*)(b0 + 8);
    xwv[1][0] = *(const u16x8*)(b1);
    xwv[1][1] = *(const u16x8*)(b1 + 8);
  }

  float cold[4][2];
  if constexpr (!T0) {
#pragma unroll
    for (int mt = 0; mt < 4; ++mt) {
      cold[mt][0] = bf2f(cT[(size_t)(feb + mt * 4 + lq) * N_NODES + n0]);
      cold[mt][1] = bf2f(cT[(size_t)(feb + mt * 4 + lq) * N_NODES + n1]);
    }
  }

  f32x4 acc[4][2];
#pragma unroll
  for (int mt = 0; mt < 4; ++mt)
#pragma unroll
    for (int nt = 0; nt < 2; ++nt)
#pragma unroll
      for (int j = 0; j < 4; ++j) acc[mt][nt][j] = 0.f;

  if constexpr (!T0) {
    __syncthreads();
    const u16* hb0 = hprev + (size_t)n0 * F + lq * 8;
    const u16* hb1 = hprev + (size_t)n1 * F + lq * 8;
#pragma unroll
    for (int ks = 0; ks < KS; ++ks) {
      bf16x8 b0 = *(const bf16x8*)(hb0 + ks * 32);
      bf16x8 b1 = *(const bf16x8*)(hb1 + ks * 32);
      bf16x8 a[4];
#pragma unroll
      for (int mt = 0; mt < 4; ++mt) {
        int r = mt * 16 + l16;
        int bo = r * ROWB + (((ks * 32 + lq * 8) * 2) ^ ((r & 7) << 4));
        a[mt] = *(const bf16x8*)(ldsb + bo);
      }
#pragma unroll
      for (int mt = 0; mt < 4; ++mt) {
        acc[mt][0] = __builtin_amdgcn_mfma_f32_16x16x32_bf16(a[mt], b0, acc[mt][0], 0, 0, 0);
        acc[mt][1] = __builtin_amdgcn_mfma_f32_16x16x32_bf16(a[mt], b1, acc[mt][1], 0, 0, 0);
      }
    }
  }

  // fused LSTM cell update (in-lane: j = gate index i,f,g,o)
#pragma unroll
  for (int mt = 0; mt < 4; ++mt) {
    int fe = feb + mt * 4 + lq;
#pragma unroll
    for (int nt = 0; nt < 2; ++nt) {
      int n = nt ? n1 : n0;
      float pi, pf, pg, po;
      if (mt < 2) {
        pi = acc[mt][nt][0] + bf2f(xwv[nt][0][(mt & 1) * 4 + 0]);
        pf = acc[mt][nt][1] + bf2f(xwv[nt][0][(mt & 1) * 4 + 1]);
        pg = acc[mt][nt][2] + bf2f(xwv[nt][0][(mt & 1) * 4 + 2]);
        po = acc[mt][nt][3] + bf2f(xwv[nt][0][(mt & 1) * 4 + 3]);
      } else {
        pi = acc[mt][nt][0] + bf2f(xwv[nt][1][(mt & 1) * 4 + 0]);
        pf = acc[mt][nt][1] + bf2f(xwv[nt][1][(mt & 1) * 4 + 1]);
        pg = acc[mt][nt][2] + bf2f(xwv[nt][1][(mt & 1) * 4 + 2]);
        po = acc[mt][nt][3] + bf2f(xwv[nt][1][(mt & 1) * 4 + 3]);
      }
      float cn;
      if constexpr (T0) cn = sigm(pi) * tanhfast(pg);
      else              cn = sigm(pf) * cold[mt][nt] + sigm(pi) * tanhfast(pg);
      float hn = sigm(po) * tanhfast(cn);
      cT[(size_t)fe * N_NODES + n] = f2bf(cn);
      tl[(w * 32 + nt * 16 + l16) * 24 + mt * 4 + lq] = f2bf(hn);
    }
  }
  __syncthreads();
  {
    int nloc = tid >> 1, q = tid & 1;
    u16x8 v = *(const u16x8*)&tl[nloc * 24 + q * 8];
    *(u16x8*)(hnext + (size_t)(col0 + nloc) * F + feb + q * 8) = v;
  }
}

// ---- mean-pool per graph + classifier -----------------------------------
__global__ void k_pool(const u16* __restrict__ h2, const float* __restrict__ Wc,
                       const float* __restrict__ bc, float* __restrict__ out) {
  __shared__ float hg[HIDF];
  int g = blockIdx.x;
  int tid = threadIdx.x;
  float s = 0.0f;
  for (int i = 0; i < NPG; ++i) s += bf2f(h2[(size_t)(g * NPG + i) * HIDF + tid]);
  hg[tid] = s * (1.0f / NPG);
  __syncthreads();
  if (tid < OUT_F) {
    float o = bc[tid];
    for (int fe = 0; fe < HIDF; ++fe) o += hg[fe] * Wc[tid * HIDF + fe];
    out[g * OUT_F + tid] = o;
  }
}

// ---- launch -------------------------------------------------------------
extern "C" void kernel_launch(void* const* d_in, const int* in_sizes, int n_in,
                              void* d_out, int out_size, void* d_ws, size_t ws_size,
                              hipStream_t stream) {
  const float* x   = (const float*)d_in[0];
  const int*   nbr = (const int*)d_in[1];
  const float* Wi1 = (const float*)d_in[2];
  const float* Wh1 = (const float*)d_in[3];
  const float* bi1 = (const float*)d_in[4];
  const float* bh1 = (const float*)d_in[5];
  const float* Ws1 = (const float*)d_in[6];
  const float* Wn1 = (const float*)d_in[7];
  const float* b1  = (const float*)d_in[8];
  const float* Wi2 = (const float*)d_in[9];
  const float* Wh2 = (const float*)d_in[10];
  const float* bi2 = (const float*)d_in[11];
  const float* bh2 = (const float*)d_in[12];
  const float* Ws2 = (const float*)d_in[13];
  const float* Wn2 = (const float*)d_in[14];
  const float* b2  = (const float*)d_in[15];
  const float* Wc  = (const float*)d_in[16];
  const float* bc  = (const float*)d_in[17];
  float* out = (float*)d_out;

  char* ws = (char*)d_ws;
  const size_t MB = 1u << 20;
  // liveness-packed (high-water 144 MB + weights):
  u16*   x16 = (u16*)(ws + 0);          //  8 MB, dead after XW1/XS1 gemms
  u16*   XW1 = (u16*)(ws + 8 * MB);     // 32 MB, dead after layer-1 recurrence
  u16*   XS1 = (u16*)(ws + 40 * MB);    // 16 MB; X2 in-place by comb1
  u16*   X2  = XS1;
  u16*   hA1 = (u16*)(ws + 56 * MB);    //  8 MB (k_layer output)
  u16*   XW2 = (u16*)(ws + 80 * MB);    // 64 MB
  u16*   XS2 = (u16*)(ws + 0);          // 16 MB (over x16+XW1-head, dead); h2o in place
  u16*   h2o = XS2;
  u16*   hA2 = (u16*)(ws + 16 * MB);    // 16 MB (over XW1, dead)
  u16*   hB2 = (u16*)(ws + 32 * MB);    // 16 MB (over XW1-tail + X2, dead by t=1)
  u16*   c2  = (u16*)(ws + 56 * MB);    // 16 MB bf16 (over hA1, dead after comb1)
  char* wr = ws + 144 * MB;
  size_t off = 0;
  auto alloc = [&](size_t bytes) { void* p = wr + off; off += (bytes + 255) & ~(size_t)255; return p; };
  u16*   Wip1 = (u16*)alloc(512 * 128 * 2);
  u16*   Whp1 = (u16*)alloc(512 * 128 * 2);
  float* bwp1 = (float*)alloc(512 * 4);
  u16*   Bs1  = (u16*)alloc(256 * 128 * 2);
  u16*   Bn1  = (u16*)alloc(256 * 128 * 2);
  u16*   Wip2 = (u16*)alloc(1024 * 256 * 2);
  u16*   Whp2 = (u16*)alloc(1024 * 256 * 2);
  float* bwp2 = (float*)alloc(1024 * 4);
  u16*   Bs2  = (u16*)alloc(256 * 256 * 2);
  u16*   Bn2  = (u16*)alloc(256 * 256 * 2);

  k_prep_x<<<dim3(N_NODES * IN_F / 4 / 256), dim3(256), 0, stream>>>(x, x16, N_NODES * IN_F / 4);
  k_prep_wg<<<dim3(256), dim3(256), 0, stream>>>(Wi1, Wh1, bi1, bh1, Wip1, Whp1, bwp1, IN_F);
  k_prep_wg<<<dim3(1024), dim3(256), 0, stream>>>(Wi2, Wh2, bi2, bh2, Wip2, Whp2, bwp2, HIDF);
  k_prep_cast<<<dim3(128), dim3(256), 0, stream>>>(Ws1, Wn1, Bs1, Bn1, 256 * 128);
  k_prep_cast<<<dim3(256), dim3(256), 0, stream>>>(Ws2, Wn2, Bs2, Bn2, 256 * 256);

  // ---- layer 1: whole recurrence in ONE kernel (Whp1 fits in LDS) ----
  k_gemm<128, 512><<<dim3(N_NODES / 64, 4), dim3(256), 0, stream>>>(x16, Wip1, bwp1, XW1);
  k_gemm<128, 256><<<dim3(N_NODES / 64, 2), dim3(256), 0, stream>>>(x16, Bs1, b1, XS1);
  k_layer<IN_F><<<dim3(N_NODES / 64), dim3(512), 0, stream>>>(XW1, Whp1, nbr, hA1);
  k_comb<128><<<dim3(N_NODES / 64, 2), dim3(256), 0, stream>>>(hA1, Bn1, XS1, X2);

  // ---- layer 2: round-11 per-step path (RBN = 16, node-groups = 128) ----
  k_gemm<256, 1024><<<dim3(N_NODES / 64, 8), dim3(256), 0, stream>>>(X2, Wip2, bwp2, XW2);
  k_gemm<256, 256><<<dim3(N_NODES / 64, 2), dim3(256), 0, stream>>>(X2, Bs2, b2, XS2);
  {
    k_step<HIDF, true><<<dim3(16, N_NODES / 256), dim3(512), 0, stream>>>(
        hA2, XW2, Whp2, nbr, 0, c2, hA2);
    u16* hc = hA2; u16* hn = hB2;
    for (int t = 1; t < DEG; ++t) {
      k_step<HIDF, false><<<dim3(16, N_NODES / 256), dim3(512), 0, stream>>>(
          hc, XW2, Whp2, nbr, t, c2, hn);
      u16* tmp = hc; hc = hn; hn = tmp;
    }
    k_comb<256><<<dim3(N_NODES / 64, 2), dim3(256), 0, stream>>>(hc, Bn2, XS2, h2o);
  }

  k_pool<<<dim3(N_GRAPHS), dim3(256), 0, stream>>>(h2o, Wc, bc, out);
}

// Round 18
// 1154.484 us; speedup vs baseline: 1.3873x; 1.0056x over previous
//
#include <hip/hip_runtime.h>

#define N_NODES 32768
#define DEG 16
#define IN_F 128
#define HIDF 256
#define N_GRAPHS 256
#define NPG 128
#define OUT_F 16

typedef unsigned short u16;
typedef unsigned int u32;
typedef __bf16 bf16x8 __attribute__((ext_vector_type(8)));
typedef float f32x4 __attribute__((ext_vector_type(4)));
typedef u16 u16x4 __attribute__((ext_vector_type(4)));
typedef u16 u16x8 __attribute__((ext_vector_type(8)));

__device__ __forceinline__ u16 f2bf(float f) {
  union { float f; unsigned u; } v; v.f = f;
  return (u16)((v.u + 0x7FFFu + ((v.u >> 16) & 1u)) >> 16);
}
__device__ __forceinline__ float bf2f(u16 b) {
  union { unsigned u; float f; } v; v.u = ((unsigned)b) << 16;
  return v.f;
}
__device__ __forceinline__ float sigm(float x) { return 1.0f / (1.0f + __expf(-x)); }
__device__ __forceinline__ float tanhfast(float x) {
  float e = __expf(2.0f * x);
  return (e - 1.0f) / (e + 1.0f);
}

// ---- prep kernels -------------------------------------------------------

__global__ void k_prep_x(const float* __restrict__ x, u16* __restrict__ out, int n4) {
  int i = blockIdx.x * blockDim.x + threadIdx.x;
  if (i < n4) {
    float4 v = ((const float4*)x)[i];
    ushort4 o;
    o.x = f2bf(v.x); o.y = f2bf(v.y); o.z = f2bf(v.z); o.w = f2bf(v.w);
    ((ushort4*)out)[i] = o;
  }
}

// Whp: gate-interleaved rows p = fe*4 + gate (MFMA C-fragment j == gate),
// always plain p-order.
// Wip/bwp: perm=0 -> plain p-order (direct MFMA A-operand / reg bias, layer1);
//          perm=1 -> lq-major within each 64-row slice (gather layout baked
//          into the XW2 GEMM output, layer2):
//   new local q = lq*16 + mt*4 + gate  <->  old local = mt*16 + lq*4 + gate
__global__ void k_prep_wg(const float* __restrict__ Wi, const float* __restrict__ Wh,
                          const float* __restrict__ bi, const float* __restrict__ bh,
                          u16* __restrict__ Wip, u16* __restrict__ Whp,
                          float* __restrict__ bwp, int F, int perm) {
  int total = 4 * F * F;
  for (int idx = blockIdx.x * blockDim.x + threadIdx.x; idx < total;
       idx += gridDim.x * blockDim.x) {
    int p = idx / F, k = idx % F;
    {  // Whp: plain
      int fe = p >> 2, g = p & 3;
      int orig = g * F + fe;
      Whp[idx] = f2bf(Wh[orig * F + k]);
    }
    {  // Wip + bwp
      int oldp = p;
      if (perm) {
        int base = p & ~63, local = p & 63;
        int lq = local >> 4, mt = (local >> 2) & 3, gate = local & 3;
        oldp = base + mt * 16 + lq * 4 + gate;
      }
      int fe = oldp >> 2, g = oldp & 3;
      int orig = g * F + fe;
      Wip[idx] = f2bf(Wi[orig * F + k]);
      if (k == 0) bwp[p] = bi[orig] + bh[orig];
    }
  }
}

__global__ void k_prep_cast(const float* __restrict__ Ws, const float* __restrict__ Wn,
                            u16* __restrict__ Bs, u16* __restrict__ Bn, int n) {
  int i = blockIdx.x * blockDim.x + threadIdx.x;
  if (i < n) { Bs[i] = f2bf(Ws[i]); Bn[i] = f2bf(Wn[i]); }
}

// ---- dense GEMM: C[M][NC] = bf16(A[M][K] @ B[NC][K]^T + bias) ------------
template <int K, int NC>
__launch_bounds__(256, 4)
__global__ void k_gemm(const u16* __restrict__ A, const u16* __restrict__ B,
                       const float* __restrict__ bias, u16* __restrict__ C) {
  constexpr int ROWB = 2 * K;
  __shared__ u16 lds[64 * K];
  char* ldsb = (char*)lds;
  const int tid = threadIdx.x;
  const int w = tid >> 6;
  const int lane = tid & 63;
  const int l16 = lane & 15, lq = lane >> 4;
  const int row0 = blockIdx.x * 64;
  const int col0 = blockIdx.y * 128;

  constexpr int CH = K / 8;
  constexpr int RPI = 256 / CH;
#pragma unroll
  for (int it = 0; it < 64 / RPI; ++it) {
    int r = tid / CH + it * RPI;
    int ch = tid % CH;
    bf16x8 v = *(const bf16x8*)(A + (size_t)(row0 + r) * K + ch * 8);
    int bo = r * ROWB + ((ch * 16) ^ ((r & 7) << 4));
    *(bf16x8*)(ldsb + bo) = v;
  }
  __syncthreads();

  f32x4 acc[4][2];
#pragma unroll
  for (int mt = 0; mt < 4; ++mt)
#pragma unroll
    for (int nt = 0; nt < 2; ++nt)
#pragma unroll
      for (int j = 0; j < 4; ++j) acc[mt][nt][j] = 0.f;

  for (int ks = 0; ks < K / 32; ++ks) {
    bf16x8 a[4];
#pragma unroll
    for (int mt = 0; mt < 4; ++mt) {
      int r = mt * 16 + l16;
      int bo = r * ROWB + (((ks * 32 + lq * 8) * 2) ^ ((r & 7) << 4));
      a[mt] = *(const bf16x8*)(ldsb + bo);
    }
#pragma unroll
    for (int nt = 0; nt < 2; ++nt) {
      int coln = col0 + w * 32 + nt * 16 + l16;
      bf16x8 b = *(const bf16x8*)(B + (size_t)coln * K + ks * 32 + lq * 8);
#pragma unroll
      for (int mt = 0; mt < 4; ++mt)
        acc[mt][nt] = __builtin_amdgcn_mfma_f32_16x16x32_bf16(a[mt], b, acc[mt][nt], 0, 0, 0);
    }
  }
#pragma unroll
  for (int mt = 0; mt < 4; ++mt)
#pragma unroll
    for (int nt = 0; nt < 2; ++nt) {
      int coln = col0 + w * 32 + nt * 16 + l16;
      float bb = bias[coln];
#pragma unroll
      for (int j = 0; j < 4; ++j) {
        int r = row0 + mt * 16 + lq * 4 + j;
        C[(size_t)r * NC + coln] = f2bf(acc[mt][nt][j] + bb);
      }
    }
}

// ---- combine GEMM: C[r][coln] = relu_bf16(XS[r][coln] + A[r]@B[coln]) ----
template <int K>
__launch_bounds__(256, 4)
__global__ void k_comb(const u16* __restrict__ A, const u16* __restrict__ B,
                       const u16* __restrict__ XS, u16* __restrict__ C) {
  constexpr int ROWB = 2 * K;
  __shared__ u16 lds[64 * K];
  char* ldsb = (char*)lds;
  const int tid = threadIdx.x;
  const int w = tid >> 6;
  const int lane = tid & 63;
  const int l16 = lane & 15, lq = lane >> 4;
  const int row0 = blockIdx.x * 64;
  const int col0 = blockIdx.y * 128;

  constexpr int CH = K / 8;
  constexpr int RPI = 256 / CH;
#pragma unroll
  for (int it = 0; it < 64 / RPI; ++it) {
    int r = tid / CH + it * RPI;
    int ch = tid % CH;
    bf16x8 v = *(const bf16x8*)(A + (size_t)(row0 + r) * K + ch * 8);
    int bo = r * ROWB + ((ch * 16) ^ ((r & 7) << 4));
    *(bf16x8*)(ldsb + bo) = v;
  }
  __syncthreads();

  f32x4 acc[4][2];
#pragma unroll
  for (int mt = 0; mt < 4; ++mt)
#pragma unroll
    for (int nt = 0; nt < 2; ++nt)
#pragma unroll
      for (int j = 0; j < 4; ++j) acc[mt][nt][j] = 0.f;

  for (int ks = 0; ks < K / 32; ++ks) {
    bf16x8 a[4];
#pragma unroll
    for (int mt = 0; mt < 4; ++mt) {
      int r = mt * 16 + l16;
      int bo = r * ROWB + (((ks * 32 + lq * 8) * 2) ^ ((r & 7) << 4));
      a[mt] = *(const bf16x8*)(ldsb + bo);
    }
#pragma unroll
    for (int nt = 0; nt < 2; ++nt) {
      int coln = col0 + w * 32 + nt * 16 + l16;
      bf16x8 b = *(const bf16x8*)(B + (size_t)coln * K + ks * 32 + lq * 8);
#pragma unroll
      for (int mt = 0; mt < 4; ++mt)
        acc[mt][nt] = __builtin_amdgcn_mfma_f32_16x16x32_bf16(a[mt], b, acc[mt][nt], 0, 0, 0);
    }
  }
#pragma unroll
  for (int mt = 0; mt < 4; ++mt)
#pragma unroll
    for (int nt = 0; nt < 2; ++nt) {
      int coln = col0 + w * 32 + nt * 16 + l16;
#pragma unroll
      for (int j = 0; j < 4; ++j) {
        int r = row0 + mt * 16 + lq * 4 + j;
        float v = acc[mt][nt][j] + bf2f(XS[(size_t)r * HIDF + coln]);
        C[(size_t)r * HIDF + coln] = f2bf(fmaxf(v, 0.f));
      }
    }
}

// ---- whole-layer LSTM aggregation for F=128, x-gather form ---------------
// gates = Wh @ h  +  Wi @ x[nbr]  + b.  One block = 64 nodes x ALL 512
// gate rows, all DEG steps internal:
//  - Wh (128KB) staged once in swizzled LDS,
//  - Wi slice (64 rows x 128) in REGISTERS per wave (16 bf16x8, loaded once),
//  - bias in registers (acc init) - no per-cell xw add,
//  - x[nbr] staged per step in a 16KB LDS buffer, gathered cooperatively
//    (256B per node per step, 4x fewer bytes than the old XW row) and
//    reg-prefetched one step ahead under the K-loops,
//  - h in 16KB LDS, c in registers. LDS total = 160KB exactly.
// 2 barriers per step.
template <int F>
__launch_bounds__(512, 2)
__global__ void k_layer(const u16* __restrict__ X,    // [N][F] node features
                        const u16* __restrict__ Wip,  // [4F][F] plain rows
                        const u16* __restrict__ Whp,  // [4F][F] plain rows
                        const float* __restrict__ bwp,// [4F] plain
                        const int* __restrict__ nbr,  // [N][DEG]
                        u16* __restrict__ hout) {     // [N][F]
  constexpr int NT = 64;
  constexpr int KS = F / 32;        // 4
  constexpr int ROWB = 2 * F;       // 256B per row
  __shared__ __align__(16) u16 Wst[8 * 64 * F];  // 128 KB
  __shared__ __align__(16) u16 hbuf[NT * F];     // 16 KB
  __shared__ __align__(16) u16 xst[NT * F];      // 16 KB
  const int tid = threadIdx.x;
  const int w = tid >> 6;
  const int lane = tid & 63;
  const int l16 = lane & 15, lq = lane >> 4;
  const int nodeg = blockIdx.x * NT;
  const int row0 = w * 64;

  // stage ALL of Whp (4F x F) swizzled, once.
#pragma unroll
  for (int it = 0; it < 16; ++it) {
    int idx = it * 512 + tid;
    int r = idx >> 4;
    int ch = idx & 15;
    bf16x8 v = *(const bf16x8*)(Whp + (size_t)r * F + ch * 8);
    int s = r >> 6, rr = r & 63;
    char* base = (char*)Wst + (size_t)s * (64 * ROWB);
    int bo = rr * ROWB + ((ch * 16) ^ ((rr & 7) << 4));
    *(bf16x8*)(base + bo) = v;
  }

  // Wi slice for this wave -> registers (A-fragment layout)
  bf16x8 awi[4][KS];
#pragma unroll
  for (int mt = 0; mt < 4; ++mt)
#pragma unroll
    for (int ks = 0; ks < KS; ++ks)
      awi[mt][ks] = *(const bf16x8*)(Wip + (size_t)(row0 + mt * 16 + l16) * F + ks * 32 + lq * 8);

  // bias -> registers (acc init; row gate-interleave makes j == gate)
  f32x4 bw[4];
#pragma unroll
  for (int mt = 0; mt < 4; ++mt)
    bw[mt] = *(const f32x4*)(bwp + row0 + mt * 16 + lq * 4);

  float c[4][4];
#pragma unroll
  for (int mt = 0; mt < 4; ++mt)
#pragma unroll
    for (int nt = 0; nt < 4; ++nt) c[mt][nt] = 0.f;

  // prologue: stage x for t=0 (chunk c: nl = c>>4, ch = c&15; 2 per thread)
#pragma unroll
  for (int rep = 0; rep < 2; ++rep) {
    int cidx = rep * 512 + tid;
    int nl = cidx >> 4, ch = cidx & 15;
    int nb = nbr[(size_t)(nodeg + nl) * DEG + 0];
    bf16x8 v = *(const bf16x8*)(X + (size_t)nb * F + ch * 8);
    int bo = nl * ROWB + ((ch * 16) ^ ((nl & 7) << 4));
    *(bf16x8*)((char*)xst + bo) = v;
  }
  __syncthreads();

  const char* wb = (const char*)Wst + (size_t)w * (64 * ROWB);
  const char* hb = (const char*)hbuf;
  char* hw = (char*)hbuf;
  const char* xb = (const char*)xst;
  char* xw = (char*)xst;

#pragma unroll 1
  for (int t = 0; t < DEG; ++t) {
    // prefetch next step's x rows into regs (landed after barrier B)
    bf16x8 xp[2];
    const bool pf = (t + 1 < DEG);
    if (pf) {
#pragma unroll
      for (int rep = 0; rep < 2; ++rep) {
        int cidx = rep * 512 + tid;
        int nl = cidx >> 4, ch = cidx & 15;
        int nb = nbr[(size_t)(nodeg + nl) * DEG + (t + 1)];
        xp[rep] = *(const bf16x8*)(X + (size_t)nb * F + ch * 8);
      }
    }

    f32x4 acc[4][4];
#pragma unroll
    for (int mt = 0; mt < 4; ++mt)
#pragma unroll
      for (int nt = 0; nt < 4; ++nt) acc[mt][nt] = bw[mt];

    // x-half: gates += Wi(regs) @ x_nbr(LDS)
#pragma unroll
    for (int ks = 0; ks < KS; ++ks) {
      bf16x8 b[4];
#pragma unroll
      for (int nt = 0; nt < 4; ++nt) {
        int nl = nt * 16 + l16;
        int bo = nl * ROWB + (((ks * 32 + lq * 8) * 2) ^ ((nl & 7) << 4));
        b[nt] = *(const bf16x8*)(xb + bo);
      }
#pragma unroll
      for (int mt = 0; mt < 4; ++mt)
#pragma unroll
        for (int nt = 0; nt < 4; ++nt)
          acc[mt][nt] = __builtin_amdgcn_mfma_f32_16x16x32_bf16(awi[mt][ks], b[nt], acc[mt][nt], 0, 0, 0);
    }
    // h-half: gates += Wh(LDS) @ h(LDS)   (h==0 at t=0)
    if (t > 0) {
#pragma unroll
      for (int ks = 0; ks < KS; ++ks) {
        bf16x8 a[4];
#pragma unroll
        for (int mt = 0; mt < 4; ++mt) {
          int rr = mt * 16 + l16;
          int bo = rr * ROWB + (((ks * 32 + lq * 8) * 2) ^ ((rr & 7) << 4));
          a[mt] = *(const bf16x8*)(wb + bo);
        }
        bf16x8 b[4];
#pragma unroll
        for (int nt = 0; nt < 4; ++nt) {
          int nl = nt * 16 + l16;
          int bo = nl * ROWB + (((ks * 32 + lq * 8) * 2) ^ ((nl & 7) << 4));
          b[nt] = *(const bf16x8*)(hb + bo);
        }
#pragma unroll
        for (int mt = 0; mt < 4; ++mt)
#pragma unroll
          for (int nt = 0; nt < 4; ++nt)
            acc[mt][nt] = __builtin_amdgcn_mfma_f32_16x16x32_bf16(a[mt], b[nt], acc[mt][nt], 0, 0, 0);
      }
    }
    __syncthreads();  // (B) all LDS reads of xst & hbuf complete

    // cell update (in-lane: j == gate i,f,g,o); c==0 at t=0 gives T0 math
#pragma unroll
    for (int mt = 0; mt < 4; ++mt) {
      int fe = w * 16 + mt * 4 + lq;
#pragma unroll
      for (int nt = 0; nt < 4; ++nt) {
        int nl = nt * 16 + l16;
        float pi = acc[mt][nt][0];
        float pf2 = acc[mt][nt][1];
        float pg = acc[mt][nt][2];
        float po = acc[mt][nt][3];
        float cn = sigm(pf2) * c[mt][nt] + sigm(pi) * tanhfast(pg);
        c[mt][nt] = cn;
        float hn = sigm(po) * tanhfast(cn);
        int bo = nl * ROWB + ((fe * 2) ^ ((nl & 7) << 4));
        *(u16*)(hw + bo) = f2bf(hn);
      }
    }
    // land prefetched x
    if (pf) {
#pragma unroll
      for (int rep = 0; rep < 2; ++rep) {
        int cidx = rep * 512 + tid;
        int nl = cidx >> 4, ch = cidx & 15;
        int bo = nl * ROWB + ((ch * 16) ^ ((nl & 7) << 4));
        *(bf16x8*)(xw + bo) = xp[rep];
      }
    }
    __syncthreads();  // (A) h_{t+1} and x_{t+1} stable for next iteration
  }

  // final h -> global, unswizzled coalesced 16B chunks
  constexpr int CPN = F / 8;
  for (int idx = tid; idx < NT * CPN; idx += 512) {
    int nl = idx / CPN, fg = idx % CPN;
    int bo = nl * ROWB + ((fg * 16) ^ ((nl & 7) << 4));
    u16x8 v = *(const u16x8*)(hb + bo);
    *(u16x8*)(hout + (size_t)(nodeg + nl) * F + fg * 8) = v;
  }
}

// ---- one LSTM step as a dense GEMM + fused cell update (F=256 path) ------
// Session-best configuration (round 11, 57.0us/step): wave-tile 64 rows x
// 32 nodes (BN=256/block, 512 thr / 8 waves), LDS-staged Whp (swizzled),
// lq-major XW gather (2x16B per thread per node, 4 lq lanes cover one 64B
// line), c state bf16 [F][N], XCD-bijective swizzle, 2 barriers.
template <int F, bool T0>
__launch_bounds__(512, 4)
__global__ void k_step(const u16* __restrict__ hprev, // [N][F] node-major
                       const u16* __restrict__ XW,    // [N][4F] lq-major slices
                       const u16* __restrict__ Whp,   // [4F][F] plain rows
                       const int* __restrict__ nbr,   // [N][DEG]
                       int t,
                       u16* __restrict__ cT,          // [F][N] bf16
                       u16* __restrict__ hnext) {     // [N][F] node-major
  constexpr int ROWB = 2 * F;
  constexpr int KS = F / 32;
  constexpr int RBN = F / 16;   // gridDim.x
  __shared__ __align__(16) u16 Alds[64 * F];
  __shared__ __align__(16) u16 tl[256 * 24];
  char* ldsb = (char*)Alds;
  const int tid = threadIdx.x;
  const int w = tid >> 6;
  const int lane = tid & 63;
  const int l16 = lane & 15, lq = lane >> 4;

  // XCD-bijective swizzle: all RBN row-blocks of node-group g share an XCD.
  const int p = blockIdx.x + RBN * blockIdx.y;
  const int s = p >> 3;
  const int rb = s % RBN;
  const int g = (p & 7) + 8 * (s / RBN);

  const int row0 = rb * 64;
  const int col0 = g * 256;
  const int feb = row0 >> 2;
  const int n0 = col0 + w * 32 + l16;
  const int n1 = n0 + 16;

  const int nb0 = nbr[(size_t)n0 * DEG + t];
  const int nb1 = nbr[(size_t)n1 * DEG + t];

  if constexpr (!T0) {
    constexpr int CH = F / 8;
    constexpr int RPI = 512 / CH;
#pragma unroll
    for (int it = 0; it < 64 / RPI; ++it) {
      int r = tid / CH + it * RPI;
      int ch = tid % CH;
      bf16x8 v = *(const bf16x8*)(Whp + (size_t)(row0 + r) * F + ch * 8);
      int bo = r * ROWB + ((ch * 16) ^ ((r & 7) << 4));
      *(bf16x8*)(ldsb + bo) = v;
    }
  }

  // XW gather: per node, this thread's 16 values are 32B contiguous
  u16x8 xwv[2][2];
  {
    const u16* b0 = XW + (size_t)nb0 * (4 * F) + row0 + lq * 16;
    const u16* b1 = XW + (size_t)nb1 * (4 * F) + row0 + lq * 16;
    xwv[0][0] = *(const u16x8*)(b0);
    xwv[0][1] = *(const u16x8*)(b0 + 8);
    xwv[1][0] = *(const u16x8*)(b1);
    xwv[1][1] = *(const u16x8*)(b1 + 8);
  }

  float cold[4][2];
  if constexpr (!T0) {
#pragma unroll
    for (int mt = 0; mt < 4; ++mt) {
      cold[mt][0] = bf2f(cT[(size_t)(feb + mt * 4 + lq) * N_NODES + n0]);
      cold[mt][1] = bf2f(cT[(size_t)(feb + mt * 4 + lq) * N_NODES + n1]);
    }
  }

  f32x4 acc[4][2];
#pragma unroll
  for (int mt = 0; mt < 4; ++mt)
#pragma unroll
    for (int nt = 0; nt < 2; ++nt)
#pragma unroll
      for (int j = 0; j < 4; ++j) acc[mt][nt][j] = 0.f;

  if constexpr (!T0) {
    __syncthreads();
    const u16* hb0 = hprev + (size_t)n0 * F + lq * 8;
    const u16* hb1 = hprev + (size_t)n1 * F + lq * 8;
#pragma unroll
    for (int ks = 0; ks < KS; ++ks) {
      bf16x8 b0 = *(const bf16x8*)(hb0 + ks * 32);
      bf16x8 b1 = *(const bf16x8*)(hb1 + ks * 32);
      bf16x8 a[4];
#pragma unroll
      for (int mt = 0; mt < 4; ++mt) {
        int r = mt * 16 + l16;
        int bo = r * ROWB + (((ks * 32 + lq * 8) * 2) ^ ((r & 7) << 4));
        a[mt] = *(const bf16x8*)(ldsb + bo);
      }
#pragma unroll
      for (int mt = 0; mt < 4; ++mt) {
        acc[mt][0] = __builtin_amdgcn_mfma_f32_16x16x32_bf16(a[mt], b0, acc[mt][0], 0, 0, 0);
        acc[mt][1] = __builtin_amdgcn_mfma_f32_16x16x32_bf16(a[mt], b1, acc[mt][1], 0, 0, 0);
      }
    }
  }

  // fused LSTM cell update (in-lane: j = gate index i,f,g,o)
#pragma unroll
  for (int mt = 0; mt < 4; ++mt) {
    int fe = feb + mt * 4 + lq;
#pragma unroll
    for (int nt = 0; nt < 2; ++nt) {
      int n = nt ? n1 : n0;
      float pi, pf, pg, po;
      if (mt < 2) {
        pi = acc[mt][nt][0] + bf2f(xwv[nt][0][(mt & 1) * 4 + 0]);
        pf = acc[mt][nt][1] + bf2f(xwv[nt][0][(mt & 1) * 4 + 1]);
        pg = acc[mt][nt][2] + bf2f(xwv[nt][0][(mt & 1) * 4 + 2]);
        po = acc[mt][nt][3] + bf2f(xwv[nt][0][(mt & 1) * 4 + 3]);
      } else {
        pi = acc[mt][nt][0] + bf2f(xwv[nt][1][(mt & 1) * 4 + 0]);
        pf = acc[mt][nt][1] + bf2f(xwv[nt][1][(mt & 1) * 4 + 1]);
        pg = acc[mt][nt][2] + bf2f(xwv[nt][1][(mt & 1) * 4 + 2]);
        po = acc[mt][nt][3] + bf2f(xwv[nt][1][(mt & 1) * 4 + 3]);
      }
      float cn;
      if constexpr (T0) cn = sigm(pi) * tanhfast(pg);
      else              cn = sigm(pf) * cold[mt][nt] + sigm(pi) * tanhfast(pg);
      float hn = sigm(po) * tanhfast(cn);
      cT[(size_t)fe * N_NODES + n] = f2bf(cn);
      tl[(w * 32 + nt * 16 + l16) * 24 + mt * 4 + lq] = f2bf(hn);
    }
  }
  __syncthreads();
  {
    int nloc = tid >> 1, q = tid & 1;
    u16x8 v = *(const u16x8*)&tl[nloc * 24 + q * 8];
    *(u16x8*)(hnext + (size_t)(col0 + nloc) * F + feb + q * 8) = v;
  }
}

// ---- mean-pool per graph + classifier -----------------------------------
__global__ void k_pool(const u16* __restrict__ h2, const float* __restrict__ Wc,
                       const float* __restrict__ bc, float* __restrict__ out) {
  __shared__ float hg[HIDF];
  int g = blockIdx.x;
  int tid = threadIdx.x;
  float s = 0.0f;
  for (int i = 0; i < NPG; ++i) s += bf2f(h2[(size_t)(g * NPG + i) * HIDF + tid]);
  hg[tid] = s * (1.0f / NPG);
  __syncthreads();
  if (tid < OUT_F) {
    float o = bc[tid];
    for (int fe = 0; fe < HIDF; ++fe) o += hg[fe] * Wc[tid * HIDF + fe];
    out[g * OUT_F + tid] = o;
  }
}

// ---- launch -------------------------------------------------------------
extern "C" void kernel_launch(void* const* d_in, const int* in_sizes, int n_in,
                              void* d_out, int out_size, void* d_ws, size_t ws_size,
                              hipStream_t stream) {
  const float* x   = (const float*)d_in[0];
  const int*   nbr = (const int*)d_in[1];
  const float* Wi1 = (const float*)d_in[2];
  const float* Wh1 = (const float*)d_in[3];
  const float* bi1 = (const float*)d_in[4];
  const float* bh1 = (const float*)d_in[5];
  const float* Ws1 = (const float*)d_in[6];
  const float* Wn1 = (const float*)d_in[7];
  const float* b1  = (const float*)d_in[8];
  const float* Wi2 = (const float*)d_in[9];
  const float* Wh2 = (const float*)d_in[10];
  const float* bi2 = (const float*)d_in[11];
  const float* bh2 = (const float*)d_in[12];
  const float* Ws2 = (const float*)d_in[13];
  const float* Wn2 = (const float*)d_in[14];
  const float* b2  = (const float*)d_in[15];
  const float* Wc  = (const float*)d_in[16];
  const float* bc  = (const float*)d_in[17];
  float* out = (float*)d_out;

  char* ws = (char*)d_ws;
  const size_t MB = 1u << 20;
  u16*   x16 = (u16*)(ws + 0);          //  8 MB, live through k_layer + XS1
  u16*   XS1 = (u16*)(ws + 40 * MB);    // 16 MB; X2 in-place by comb1
  u16*   X2  = XS1;
  u16*   hA1 = (u16*)(ws + 56 * MB);    //  8 MB (k_layer output)
  u16*   XW2 = (u16*)(ws + 80 * MB);    // 64 MB
  u16*   XS2 = (u16*)(ws + 0);          // 16 MB (over x16, dead); h2o in place
  u16*   h2o = XS2;
  u16*   hA2 = (u16*)(ws + 16 * MB);    // 16 MB
  u16*   hB2 = (u16*)(ws + 32 * MB);    // 16 MB
  u16*   c2  = (u16*)(ws + 56 * MB);    // 16 MB bf16 (over hA1, dead after comb1)
  char* wr = ws + 144 * MB;
  size_t off = 0;
  auto alloc = [&](size_t bytes) { void* p = wr + off; off += (bytes + 255) & ~(size_t)255; return p; };
  u16*   Wip1 = (u16*)alloc(512 * 128 * 2);
  u16*   Whp1 = (u16*)alloc(512 * 128 * 2);
  float* bwp1 = (float*)alloc(512 * 4);
  u16*   Bs1  = (u16*)alloc(256 * 128 * 2);
  u16*   Bn1  = (u16*)alloc(256 * 128 * 2);
  u16*   Wip2 = (u16*)alloc(1024 * 256 * 2);
  u16*   Whp2 = (u16*)alloc(1024 * 256 * 2);
  float* bwp2 = (float*)alloc(1024 * 4);
  u16*   Bs2  = (u16*)alloc(256 * 256 * 2);
  u16*   Bn2  = (u16*)alloc(256 * 256 * 2);

  k_prep_x<<<dim3(N_NODES * IN_F / 4 / 256), dim3(256), 0, stream>>>(x, x16, N_NODES * IN_F / 4);
  k_prep_wg<<<dim3(256), dim3(256), 0, stream>>>(Wi1, Wh1, bi1, bh1, Wip1, Whp1, bwp1, IN_F, 0);
  k_prep_wg<<<dim3(1024), dim3(256), 0, stream>>>(Wi2, Wh2, bi2, bh2, Wip2, Whp2, bwp2, HIDF, 1);
  k_prep_cast<<<dim3(128), dim3(256), 0, stream>>>(Ws1, Wn1, Bs1, Bn1, 256 * 128);
  k_prep_cast<<<dim3(256), dim3(256), 0, stream>>>(Ws2, Wn2, Bs2, Bn2, 256 * 256);

  // ---- layer 1: whole recurrence in ONE kernel, raw-x gather ----
  k_gemm<128, 256><<<dim3(N_NODES / 64, 2), dim3(256), 0, stream>>>(x16, Bs1, b1, XS1);
  k_layer<IN_F><<<dim3(N_NODES / 64), dim3(512), 0, stream>>>(x16, Wip1, Whp1, bwp1, nbr, hA1);
  k_comb<128><<<dim3(N_NODES / 64, 2), dim3(256), 0, stream>>>(hA1, Bn1, XS1, X2);

  // ---- layer 2: round-11 per-step path (RBN = 16, node-groups = 128) ----
  k_gemm<256, 1024><<<dim3(N_NODES / 64, 8), dim3(256), 0, stream>>>(X2, Wip2, bwp2, XW2);
  k_gemm<256, 256><<<dim3(N_NODES / 64, 2), dim3(256), 0, stream>>>(X2, Bs2, b2, XS2);
  {
    k_step<HIDF, true><<<dim3(16, N_NODES / 256), dim3(512), 0, stream>>>(
        hA2, XW2, Whp2, nbr, 0, c2, hA2);
    u16* hc = hA2; u16* hn = hB2;
    for (int t = 1; t < DEG; ++t) {
      k_step<HIDF, false><<<dim3(16, N_NODES / 256), dim3(512), 0, stream>>>(
          hc, XW2, Whp2, nbr, t, c2, hn);
      u16* tmp = hc; hc = hn; hn = tmp;
    }
    k_comb<256><<<dim3(N_NODES / 64, 2), dim3(256), 0, stream>>>(hc, Bn2, XS2, h2o);
  }

  k_pool<<<dim3(N_GRAPHS), dim3(256), 0, stream>>>(h2o, Wc, bc, out);
}